// Round 3
// baseline (1297.879 us; speedup 1.0000x reference)
//
#include <hip/hip_runtime.h>
#include <cstdint>

// ---------------------------------------------------------------------------
// CVTransformer: L=4, D=256, H=8, DH=32, WS=128, FF=1024, B=2, N=8192
// fp32 residual stream X[16384][512]; all matmuls bf16 MFMA GEMMs, K=2D.
// GEMM: 8-phase 256-row schedule (T3+T4 counted vmcnt, T5 setprio, T2 swizzle)
// ---------------------------------------------------------------------------

typedef __bf16 bf16x8 __attribute__((ext_vector_type(8)));
typedef float  f32x4  __attribute__((ext_vector_type(4)));

#define M_TOK 16384
#define LDX   512

__device__ __forceinline__ unsigned short f2bf(float f) {
    union { float f; unsigned int u; } v; v.f = f;
    unsigned int r = v.u + 0x7FFFu + ((v.u >> 16) & 1u);
    return (unsigned short)(r >> 16);
}

__device__ __forceinline__ void async16(const void* g, void* l) {
    __builtin_amdgcn_global_load_lds(
        (const __attribute__((address_space(1))) void*)g,
        (__attribute__((address_space(3))) void*)l, 16, 0, 0);
}

// ----------------------------- elementwise ---------------------------------

__global__ __launch_bounds__(256) void copyin_kernel(const float* __restrict__ xr,
                                                     const float* __restrict__ xi,
                                                     float* __restrict__ X) {
    int idx = blockIdx.x * 256 + threadIdx.x;       // float4 over [16384][128]
    int t = idx >> 7, c4 = idx & 127;
    float4 v = (c4 < 64) ? ((const float4*)xr)[t * 64 + c4]
                         : ((const float4*)xi)[t * 64 + (c4 - 64)];
    ((float4*)X)[idx] = v;
}

__global__ __launch_bounds__(256) void unpack_kernel(const float* __restrict__ X,
                                                     float* __restrict__ out) {
    int idx = blockIdx.x * 256 + threadIdx.x;       // float4 over [2][16384][64]
    int p = idx >> 20;                               // 1048576 f4 per plane
    int rem = idx & 1048575;
    int t = rem >> 6, d4 = rem & 63;
    ((float4*)out)[idx] = ((const float4*)X)[t * 128 + p * 64 + d4];
}

// ----------------------------- weight packing ------------------------------
// Packed layout: Bt[n][k], k = 0..2D-1 (real then imag input planes).

__global__ __launch_bounds__(256) void pack_qkv_kernel(
    const float* __restrict__ Wq_r, const float* __restrict__ Wq_i,
    const float* __restrict__ Wk_r, const float* __restrict__ Wk_i,
    const float* __restrict__ Wv_r, const float* __restrict__ Wv_i,
    unsigned short* __restrict__ out) {
    int idx = blockIdx.x * 256 + threadIdx.x;       // L*1536*512
    int l = idx / 786432;
    int rem = idx - l * 786432;
    int n = rem >> 9, k = rem & 511;
    int blk = n >> 8;                                // 0..5 : qr qi kr ki vr vi
    int no = n & 255, kk = k & 255;
    bool khi = (k >= 256);
    bool imag = (blk & 1);
    const float *Wr, *Wi;
    int proj = blk >> 1;
    if (proj == 0)      { Wr = Wq_r; Wi = Wq_i; }
    else if (proj == 1) { Wr = Wk_r; Wi = Wk_i; }
    else                { Wr = Wv_r; Wi = Wv_i; }
    int wi = l * 65536 + kk * 256 + no;
    float val = !imag ? (khi ? -Wi[wi] : Wr[wi])
                      : (khi ?  Wr[wi] : Wi[wi]);
    out[idx] = f2bf(val);
}

__global__ __launch_bounds__(256) void pack_o_kernel(
    const float* __restrict__ Wo_r, const float* __restrict__ Wo_i,
    unsigned short* __restrict__ out) {
    int idx = blockIdx.x * 256 + threadIdx.x;       // L*512*512
    int l = idx >> 18;
    int rem = idx & 262143;
    int n = rem >> 9, k = rem & 511;
    bool imag = (n >= 256);
    int no = n & 255, kk = k & 255;
    bool khi = (k >= 256);
    int wi = l * 65536 + kk * 256 + no;
    float val = !imag ? (khi ? -Wo_i[wi] : Wo_r[wi])
                      : (khi ?  Wo_r[wi] : Wo_i[wi]);
    out[idx] = f2bf(val);
}

__global__ __launch_bounds__(256) void pack_ffn1_kernel(
    const float* __restrict__ W1_r, const float* __restrict__ W1_i,
    unsigned short* __restrict__ out) {
    int idx = blockIdx.x * 256 + threadIdx.x;       // L*2048*512
    int l = idx >> 20;
    int rem = idx & 1048575;
    int n = rem >> 9, k = rem & 511;
    bool imag = (n >= 1024);
    int no = imag ? n - 1024 : n;
    int kk = k & 255;
    bool khi = (k >= 256);
    int wi = l * 262144 + kk * 1024 + no;
    float val = !imag ? (khi ? -W1_i[wi] : W1_r[wi])
                      : (khi ?  W1_r[wi] : W1_i[wi]);
    out[idx] = f2bf(val);
}

__global__ __launch_bounds__(256) void pack_ffn2_kernel(
    const float* __restrict__ W2_r, const float* __restrict__ W2_i,
    unsigned short* __restrict__ out) {
    int idx = blockIdx.x * 256 + threadIdx.x;       // L*512*2048
    int l = idx >> 20;
    int rem = idx & 1048575;
    int n = rem >> 11, k = rem & 2047;
    bool imag = (n >= 256);
    int no = n & 255;
    int kk = k & 1023;
    bool khi = (k >= 1024);
    int wi = l * 262144 + kk * 256 + no;
    float val = !imag ? (khi ? -W2_i[wi] : W2_r[wi])
                      : (khi ?  W2_r[wi] : W2_i[wi]);
    out[idx] = f2bf(val);
}

__global__ __launch_bounds__(256) void pack_bias_kernel(
    const float* __restrict__ b1r, const float* __restrict__ b1i,
    const float* __restrict__ b2r, const float* __restrict__ b2i,
    float* __restrict__ B1, float* __restrict__ B2) {
    int idx = blockIdx.x * 256 + threadIdx.x;       // 4*2048 + 4*512 = 10240
    if (idx < 8192) {
        int l = idx >> 11, n = idx & 2047;
        bool imag = (n >= 1024);
        int no = imag ? n - 1024 : n;
        int bi = l * 1024 + no;
        B1[idx] = imag ? (b1r[bi] + b1i[bi]) : (b1r[bi] - b1i[bi]);
    } else {
        int i2 = idx - 8192;
        int l = i2 >> 9, n = i2 & 511;
        bool imag = (n >= 256);
        int no = n & 255;
        int bi = l * 256 + no;
        B2[i2] = imag ? (b2r[bi] + b2i[bi]) : (b2r[bi] - b2i[bi]);
    }
}

// ----------------------------- rmsnorm -------------------------------------

__global__ __launch_bounds__(256) void rmsnorm_kernel(const float* __restrict__ X,
                                                      const float* __restrict__ scale,
                                                      unsigned short* __restrict__ out) {
    int row = blockIdx.x * 4 + (threadIdx.x >> 6);
    int lane = threadIdx.x & 63;
    const float4* xrow = (const float4*)(X + (size_t)row * LDX);
    float4 xr = xrow[lane];
    float4 xi = xrow[64 + lane];
    float ss = xr.x * xr.x + xr.y * xr.y + xr.z * xr.z + xr.w * xr.w
             + xi.x * xi.x + xi.y * xi.y + xi.z * xi.z + xi.w * xi.w;
#pragma unroll
    for (int m = 1; m < 64; m <<= 1) ss += __shfl_xor(ss, m);
    float inv = 1.0f / sqrtf(ss * (1.0f / 256.0f) + 1e-8f);
    float4 sc = ((const float4*)scale)[lane];
    ushort4 o0, o1;
    o0.x = f2bf(xr.x * inv * sc.x); o0.y = f2bf(xr.y * inv * sc.y);
    o0.z = f2bf(xr.z * inv * sc.z); o0.w = f2bf(xr.w * inv * sc.w);
    o1.x = f2bf(xi.x * inv * sc.x); o1.y = f2bf(xi.y * inv * sc.y);
    o1.z = f2bf(xi.z * inv * sc.z); o1.w = f2bf(xi.w * inv * sc.w);
    ushort4* orow = (ushort4*)(out + (size_t)row * LDX);
    orow[lane] = o0;
    orow[64 + lane] = o1;
}

// ----------------------------- GEMM: 8-phase 256-row schedule ---------------
// C[M,N] = A[M,K](bf16) @ Bt[N,K]^T(bf16).  BM=256, BN=256|128, BK=64.
// 8 waves (wm=wave>>2, wn=wave&3); per-wave output: rows {wm*64..+63} in each
// M-half, cols {wn*(FN*16)..} in each N-half.  LDS: A 4x16KB halves + B 4xHB.
// Per phase: quadrant q of tile tt: ds_read subtile + 1 half-tile prefetch +
// barrier + lgkmcnt(0) + setprio-wrapped MFMA + (counted vmcnt at q==3) + bar.
// Stage schedule (iter = tiles t,t+1): p0:B0(t+1) p1:A0(t+2) p2:B1(t+2)
// p3:A1(t+2) p4:B0(t+2) p5:A0(t+3) p6:B1(t+3) p7:A1(t+3), wrap mod NT.
// MODE 0: bf16 out. 1: +bias,GELU,bf16. 2: +bias(optional), fp32 += into X.

template <int BN, int MODE>
__global__ __launch_bounds__(512, 1) void gemm8_kernel(
    const unsigned short* __restrict__ A, const unsigned short* __restrict__ Bt,
    unsigned short* __restrict__ Obf, const float* __restrict__ bias,
    float* __restrict__ Xres, int K, int N) {
    constexpr int FN = BN / 128;          // B frags per N-half per wave
    constexpr int HB = BN * 64;           // bytes per B half-tile
    constexpr int LB = BN / 128;          // loads/thread per B half stage
    __shared__ __align__(16) char smem[65536 + 4 * HB];
    const int tid = threadIdx.x;
    const int lane = tid & 63;
    const int wave = tid >> 6;
    const int g = lane >> 4, rl = lane & 15;
    const int wm = wave >> 2, wn = wave & 3;
    const int tM = blockIdx.y, tN = blockIdx.x;
    const int NT = K >> 6, NTM = NT - 1, NIT = NT >> 1;

    auto stageA = [&](int t, int mh) {
        int tt = t & NTM;
        const unsigned short* src = A + ((size_t)(tM * 256 + mh * 128)) * K + tt * 64;
        char* dst = smem + ((tt & 1) * 2 + mh) * 16384;
#pragma unroll
        for (int it = 0; it < 2; ++it) {
            int s = it * 512 + tid;
            int r = s >> 3, c = (s & 7) ^ (r & 7);
            async16(src + (size_t)r * K + c * 8, dst + (it * 512 + wave * 64) * 16);
        }
    };
    auto stageB = [&](int t, int nh) {
        int tt = t & NTM;
        const unsigned short* src = Bt + ((size_t)(tN * BN + nh * (BN / 2))) * K + tt * 64;
        char* dst = smem + 65536 + ((tt & 1) * 2 + nh) * HB;
#pragma unroll
        for (int it = 0; it < LB; ++it) {
            int s = it * 512 + tid;
            int r = s >> 3, c = (s & 7) ^ (r & 7);
            async16(src + (size_t)r * K + c * 8, dst + (it * 512 + wave * 64) * 16);
        }
    };

    f32x4 acc[2][2][4][FN];
#pragma unroll
    for (int a = 0; a < 2; ++a)
#pragma unroll
        for (int b = 0; b < 2; ++b)
#pragma unroll
            for (int c = 0; c < 4; ++c)
#pragma unroll
                for (int d = 0; d < FN; ++d)
#pragma unroll
                    for (int v = 0; v < 4; ++v) acc[a][b][c][d][v] = 0.0f;

    bf16x8 aF[4][2], bF[FN][2];

    // prologue: tile0 fully + A0,B1,A1 of tile1 (leaves exactly 2LA+LB in flight)
    stageA(0, 0); stageA(0, 1); stageB(0, 0); stageB(0, 1);
    stageA(1, 0); stageB(1, 1); stageA(1, 1);
    if constexpr (BN == 256) asm volatile("s_waitcnt vmcnt(6)" ::: "memory");
    else                     asm volatile("s_waitcnt vmcnt(5)" ::: "memory");
    __builtin_amdgcn_s_barrier();

    for (int i = 0; i < NIT; ++i) {
        const int t0 = 2 * i;
#pragma unroll
        for (int p = 0; p < 8; ++p) {
            const int q = p & 3;                    // quadrant
            const int tt = t0 + (p >> 2);
            const int b = tt & 1;
            const int mh = q >> 1;                  // 0,0,1,1
            const int nh = (q == 1 || q == 2) ? 1 : 0;
            if (q == 0 || q == 2) {                 // new A M-half
                char* base = smem + (b * 2 + mh) * 16384;
#pragma unroll
                for (int fm = 0; fm < 4; ++fm) {
                    int hr = wm * 64 + fm * 16 + rl;
#pragma unroll
                    for (int ks = 0; ks < 2; ++ks) {
                        int c = ks * 4 + g;
                        aF[fm][ks] = *(const bf16x8*)(base + hr * 128 + ((c ^ (hr & 7)) << 4));
                    }
                }
            }
            if (q != 2) {                           // new B N-half (q==2 reuses)
                char* base = smem + 65536 + (b * 2 + nh) * HB;
#pragma unroll
                for (int fn = 0; fn < FN; ++fn) {
                    int hr = wn * (FN * 16) + fn * 16 + rl;
#pragma unroll
                    for (int ks = 0; ks < 2; ++ks) {
                        int c = ks * 4 + g;
                        bF[fn][ks] = *(const bf16x8*)(base + hr * 128 + ((c ^ (hr & 7)) << 4));
                    }
                }
            }
            switch (p) {                            // 1 half-tile prefetch
                case 0: stageB(t0 + 1, 0); break;
                case 1: stageA(t0 + 2, 0); break;
                case 2: stageB(t0 + 2, 1); break;
                case 3: stageA(t0 + 2, 1); break;
                case 4: stageB(t0 + 2, 0); break;
                case 5: stageA(t0 + 3, 0); break;
                case 6: stageB(t0 + 3, 1); break;
                case 7: stageA(t0 + 3, 1); break;
            }
            __builtin_amdgcn_s_barrier();
            asm volatile("s_waitcnt lgkmcnt(0)" ::: "memory");
            __builtin_amdgcn_s_setprio(1);
#pragma unroll
            for (int fm = 0; fm < 4; ++fm)
#pragma unroll
                for (int fn = 0; fn < FN; ++fn)
#pragma unroll
                    for (int ks = 0; ks < 2; ++ks)
                        acc[mh][nh][fm][fn] = __builtin_amdgcn_mfma_f32_16x16x32_bf16(
                            aF[fm][ks], bF[fn][ks], acc[mh][nh][fm][fn], 0, 0, 0);
            __builtin_amdgcn_s_setprio(0);
            if (q == 3) {
                if constexpr (BN == 256) asm volatile("s_waitcnt vmcnt(6)" ::: "memory");
                else                     asm volatile("s_waitcnt vmcnt(5)" ::: "memory");
            }
            __builtin_amdgcn_s_barrier();
        }
    }
    asm volatile("s_waitcnt vmcnt(0)" ::: "memory");

#pragma unroll
    for (int mh = 0; mh < 2; ++mh)
#pragma unroll
        for (int nh = 0; nh < 2; ++nh)
#pragma unroll
            for (int fm = 0; fm < 4; ++fm)
#pragma unroll
                for (int fn = 0; fn < FN; ++fn)
#pragma unroll
                    for (int v = 0; v < 4; ++v) {
                        int row = tM * 256 + mh * 128 + wm * 64 + fm * 16 + g * 4 + v;
                        int col = tN * BN + nh * (BN / 2) + wn * (FN * 16) + fn * 16 + rl;
                        float val = acc[mh][nh][fm][fn][v];
                        if (MODE == 0) {
                            Obf[(size_t)row * N + col] = f2bf(val);
                        } else if (MODE == 1) {
                            float x = val + bias[col];
                            float ge = 0.5f * x * (1.0f + erff(x * 0.70710678118654752f));
                            Obf[(size_t)row * N + col] = f2bf(ge);
                        } else {
                            float x = val + (bias ? bias[col] : 0.0f);
                            Xres[(size_t)row * LDX + col] += x;
                        }
                    }
}

// ----------------------------- windowed attention --------------------------
// One block per (window, head, batch).  QKV buffer: [16384][1536] bf16,
// cols: qr qi kr ki vr vi (256 each).  Output: [16384][512] bf16 (or|oi).

#define AT_KOFF 16384
#define AT_VOFF 34816
#define AT_ROFF 52224

__global__ __launch_bounds__(256) void attn_kernel(
    const unsigned short* __restrict__ qkv, const float* __restrict__ relb_g,
    unsigned short* __restrict__ attout) {
    __shared__ __align__(16) char smem[53264];
    const int tid = threadIdx.x;
    const int lane = tid & 63;
    const int wq = tid >> 6;
    const int g = lane >> 4;
    const int rl = lane & 15;
    const int w = blockIdx.x, h = blockIdx.y, b = blockIdx.z;
    const int tok0 = b * 8192 + w * 128;
    float* relb = (float*)(smem + AT_ROFF);

    for (int i = tid; i < 257; i += 256) relb[i] = relb_g[i];

    // stage Qc,Kc [128][64] bf16 (real|imag along K), XOR chunk swizzle
#pragma unroll
    for (int it = 0; it < 4; ++it) {
        int s = it * 256 + tid;
        int r = s >> 3;
        int c = (s & 7) ^ (r & 7);
        int colq = (c < 4) ? (h * 32 + c * 8) : (256 + h * 32 + (c - 4) * 8);
        const unsigned short* rowp = qkv + (size_t)(tok0 + r) * 1536;
        *(float4*)(smem + s * 16) = *(const float4*)(rowp + colq);
        *(float4*)(smem + AT_KOFF + s * 16) = *(const float4*)(rowp + colq + 512);
    }
    // stage Vt [64][136] bf16: Vt[d'][j] ; d' 0..31 = vr, 32..63 = vi
#pragma unroll
    for (int it = 0; it < 4; ++it) {
        int e = it * 256 + tid;
        int j = e >> 3;
        int d0 = (e & 7) * 8;
        int colv = (d0 < 32) ? (1024 + h * 32 + d0) : (1280 + h * 32 + (d0 - 32));
        float4 vv = *(const float4*)(qkv + (size_t)(tok0 + j) * 1536 + colv);
        const unsigned short* u = (const unsigned short*)&vv;
#pragma unroll
        for (int k = 0; k < 8; ++k)
            *(unsigned short*)(smem + AT_VOFF + ((d0 + k) * 136 + j) * 2) = u[k];
    }
    __syncthreads();

    // S = Qc @ Kc^T  (covers qr.kr + qi.ki via K=64)
    f32x4 accS[2][8];
#pragma unroll
    for (int i = 0; i < 2; ++i)
#pragma unroll
        for (int j = 0; j < 8; ++j)
#pragma unroll
            for (int v = 0; v < 4; ++v) accS[i][j][v] = 0.0f;

#pragma unroll
    for (int ks = 0; ks < 2; ++ks) {
        bf16x8 qf[2], kf[8];
        int c = ks * 4 + g;
#pragma unroll
        for (int fm = 0; fm < 2; ++fm) {
            int r = wq * 32 + fm * 16 + rl;
            qf[fm] = *(const bf16x8*)(smem + r * 128 + ((c ^ (r & 7)) << 4));
        }
#pragma unroll
        for (int fn = 0; fn < 8; ++fn) {
            int r = fn * 16 + rl;
            kf[fn] = *(const bf16x8*)(smem + AT_KOFF + r * 128 + ((c ^ (r & 7)) << 4));
        }
#pragma unroll
        for (int fm = 0; fm < 2; ++fm)
#pragma unroll
            for (int fn = 0; fn < 8; ++fn)
                accS[fm][fn] = __builtin_amdgcn_mfma_f32_16x16x32_bf16(
                    qf[fm], kf[fn], accS[fm][fn], 0, 0, 0);
    }

    // softmax (rows live in 16-lane groups)
#pragma unroll
    for (int fm = 0; fm < 2; ++fm)
#pragma unroll
        for (int v = 0; v < 4; ++v) {
            int i = wq * 32 + fm * 16 + g * 4 + v;
            float m = -1e30f;
#pragma unroll
            for (int fn = 0; fn < 8; ++fn) {
                int j = fn * 16 + rl;
                float s = accS[fm][fn][v] * 0.17677669529663687f + relb[j - i + 128];
                accS[fm][fn][v] = s;
                m = fmaxf(m, s);
            }
            m = fmaxf(m, __shfl_xor(m, 1));
            m = fmaxf(m, __shfl_xor(m, 2));
            m = fmaxf(m, __shfl_xor(m, 4));
            m = fmaxf(m, __shfl_xor(m, 8));
            float sum = 0.0f;
#pragma unroll
            for (int fn = 0; fn < 8; ++fn) {
                float p = __expf(accS[fm][fn][v] - m);
                accS[fm][fn][v] = p;
                sum += p;
            }
            sum += __shfl_xor(sum, 1);
            sum += __shfl_xor(sum, 2);
            sum += __shfl_xor(sum, 4);
            sum += __shfl_xor(sum, 8);
            float inv = 1.0f / sum;
#pragma unroll
            for (int fn = 0; fn < 8; ++fn) accS[fm][fn][v] *= inv;
        }

    __syncthreads();   // all Qc/Kc reads done before P overwrites them

    // write P [128][136] bf16 at offset 0
#pragma unroll
    for (int fm = 0; fm < 2; ++fm)
#pragma unroll
        for (int fn = 0; fn < 8; ++fn)
#pragma unroll
            for (int v = 0; v < 4; ++v) {
                int i = wq * 32 + fm * 16 + g * 4 + v;
                int j = fn * 16 + rl;
                ((unsigned short*)smem)[i * 136 + j] = f2bf(accS[fm][fn][v]);
            }
    __syncthreads();

    // O = P @ V   (combined cols: 0..31 = or, 32..63 = oi)
    f32x4 accO[2][4];
#pragma unroll
    for (int i = 0; i < 2; ++i)
#pragma unroll
        for (int j = 0; j < 4; ++j)
#pragma unroll
            for (int v = 0; v < 4; ++v) accO[i][j][v] = 0.0f;

#pragma unroll
    for (int ks = 0; ks < 4; ++ks) {
        bf16x8 pf[2], vf[4];
#pragma unroll
        for (int fm = 0; fm < 2; ++fm) {
            int r = wq * 32 + fm * 16 + rl;
            pf[fm] = *(const bf16x8*)(smem + r * 272 + ks * 64 + g * 16);
        }
#pragma unroll
        for (int fn = 0; fn < 4; ++fn) {
            int n = fn * 16 + rl;
            vf[fn] = *(const bf16x8*)(smem + AT_VOFF + n * 272 + ks * 64 + g * 16);
        }
#pragma unroll
        for (int fm = 0; fm < 2; ++fm)
#pragma unroll
            for (int fn = 0; fn < 4; ++fn)
                accO[fm][fn] = __builtin_amdgcn_mfma_f32_16x16x32_bf16(
                    pf[fm], vf[fn], accO[fm][fn], 0, 0, 0);
    }

#pragma unroll
    for (int fm = 0; fm < 2; ++fm)
#pragma unroll
        for (int fn = 0; fn < 4; ++fn)
#pragma unroll
            for (int v = 0; v < 4; ++v) {
                int i = wq * 32 + fm * 16 + g * 4 + v;
                int dc = fn * 16 + rl;
                int col = (dc < 32) ? (h * 32 + dc) : (256 + h * 32 + (dc - 32));
                attout[(size_t)(tok0 + i) * 512 + col] = f2bf(accO[fm][fn][v]);
            }
}

// ----------------------------- launch --------------------------------------

extern "C" void kernel_launch(void* const* d_in, const int* in_sizes, int n_in,
                              void* d_out, int out_size, void* d_ws, size_t ws_size,
                              hipStream_t stream) {
    const float* x_real = (const float*)d_in[0];
    const float* x_imag = (const float*)d_in[1];
    const float* Wq_r = (const float*)d_in[2];
    const float* Wq_i = (const float*)d_in[3];
    const float* Wk_r = (const float*)d_in[4];
    const float* Wk_i = (const float*)d_in[5];
    const float* Wv_r = (const float*)d_in[6];
    const float* Wv_i = (const float*)d_in[7];
    const float* Wo_r = (const float*)d_in[8];
    const float* Wo_i = (const float*)d_in[9];
    const float* rel_bias = (const float*)d_in[10];
    const float* norm1 = (const float*)d_in[11];
    const float* norm2 = (const float*)d_in[12];
    const float* W1_r = (const float*)d_in[13];
    const float* b1_r = (const float*)d_in[14];
    const float* W1_i = (const float*)d_in[15];
    const float* b1_i = (const float*)d_in[16];
    const float* W2_r = (const float*)d_in[17];
    const float* b2_r = (const float*)d_in[18];
    const float* W2_i = (const float*)d_in[19];
    const float* b2_i = (const float*)d_in[20];

    char* ws = (char*)d_ws;
    float*          X    = (float*)(ws + 0);                    // 32 MB
    unsigned short* NRM  = (unsigned short*)(ws + 33554432);    // 16 MB
    unsigned short* QKVH = (unsigned short*)(ws + 50331648);    // 64 MB (QKV / FFN-H)
    unsigned short* ATTO = (unsigned short*)(ws + 117440512);   // 16 MB
    unsigned short* WQKV = (unsigned short*)(ws + 134217728);   // 6 MB
    unsigned short* WO   = (unsigned short*)(ws + 140509184);   // 2 MB
    unsigned short* W1P  = (unsigned short*)(ws + 142606336);   // 8 MB
    unsigned short* W2P  = (unsigned short*)(ws + 150994944);   // 8 MB
    float*          B1   = (float*)(ws + 159383552);
    float*          B2   = (float*)(ws + 159416320);

    copyin_kernel<<<8192, 256, 0, stream>>>(x_real, x_imag, X);
    pack_qkv_kernel<<<12288, 256, 0, stream>>>(Wq_r, Wq_i, Wk_r, Wk_i, Wv_r, Wv_i, WQKV);
    pack_o_kernel<<<4096, 256, 0, stream>>>(Wo_r, Wo_i, WO);
    pack_ffn1_kernel<<<16384, 256, 0, stream>>>(W1_r, W1_i, W1P);
    pack_ffn2_kernel<<<16384, 256, 0, stream>>>(W2_r, W2_i, W2P);
    pack_bias_kernel<<<40, 256, 0, stream>>>(b1_r, b1_i, b2_r, b2_i, B1, B2);

    for (int l = 0; l < 4; ++l) {
        rmsnorm_kernel<<<4096, 256, 0, stream>>>(X, norm1 + l * 256, NRM);
        gemm8_kernel<128, 0><<<dim3(12, 64), 512, 0, stream>>>(
            NRM, WQKV + (size_t)l * 786432, QKVH, nullptr, nullptr, 512, 1536);
        attn_kernel<<<dim3(64, 8, 2), 256, 0, stream>>>(QKVH, rel_bias + l * 257, ATTO);
        gemm8_kernel<128, 2><<<dim3(4, 64), 512, 0, stream>>>(
            ATTO, WO + (size_t)l * 262144, nullptr, nullptr, X, 512, 512);
        rmsnorm_kernel<<<4096, 256, 0, stream>>>(X, norm2 + l * 256, NRM);
        gemm8_kernel<256, 1><<<dim3(8, 64), 512, 0, stream>>>(
            NRM, W1P + (size_t)l * 1048576, QKVH, B1 + l * 2048, nullptr, 512, 2048);
        gemm8_kernel<128, 2><<<dim3(4, 64), 512, 0, stream>>>(
            QKVH, W2P + (size_t)l * 1048576, nullptr, B2 + l * 512, X, 2048, 512);
    }
    unpack_kernel<<<8192, 256, 0, stream>>>(X, (float*)d_out);
}

// Round 4
// 1089.056 us; speedup vs baseline: 1.1917x; 1.1917x over previous
//
#include <hip/hip_runtime.h>
#include <cstdint>

// ---------------------------------------------------------------------------
// CVTransformer: L=4, D=256, H=8, DH=32, WS=128, FF=1024, B=2, N=8192
// fp32 residual stream X[16384][512]; all matmuls bf16 MFMA GEMMs, K=2D.
// GEMM: 128x128 tile, 4 waves, double-buffered LDS prefetch (T3-minimum),
// bijective XCD-chunk swizzle (T1), XOR chunk swizzle in LDS (T2, 0-conflict).
// ---------------------------------------------------------------------------

typedef __bf16 bf16x8 __attribute__((ext_vector_type(8)));
typedef float  f32x4  __attribute__((ext_vector_type(4)));

#define M_TOK 16384
#define LDX   512

__device__ __forceinline__ unsigned short f2bf(float f) {
    union { float f; unsigned int u; } v; v.f = f;
    unsigned int r = v.u + 0x7FFFu + ((v.u >> 16) & 1u);
    return (unsigned short)(r >> 16);
}

__device__ __forceinline__ void async16(const void* g, void* l) {
    __builtin_amdgcn_global_load_lds(
        (const __attribute__((address_space(1))) void*)g,
        (__attribute__((address_space(3))) void*)l, 16, 0, 0);
}

// ----------------------------- elementwise ---------------------------------

__global__ __launch_bounds__(256) void copyin_kernel(const float* __restrict__ xr,
                                                     const float* __restrict__ xi,
                                                     float* __restrict__ X) {
    int idx = blockIdx.x * 256 + threadIdx.x;       // float4 over [16384][128]
    int t = idx >> 7, c4 = idx & 127;
    float4 v = (c4 < 64) ? ((const float4*)xr)[t * 64 + c4]
                         : ((const float4*)xi)[t * 64 + (c4 - 64)];
    ((float4*)X)[idx] = v;
}

__global__ __launch_bounds__(256) void unpack_kernel(const float* __restrict__ X,
                                                     float* __restrict__ out) {
    int idx = blockIdx.x * 256 + threadIdx.x;       // float4 over [2][16384][64]
    int p = idx >> 20;                               // 1048576 f4 per plane
    int rem = idx & 1048575;
    int t = rem >> 6, d4 = rem & 63;
    ((float4*)out)[idx] = ((const float4*)X)[t * 128 + p * 64 + d4];
}

// ----------------------------- weight packing ------------------------------
// Packed layout: Bt[n][k], k = 0..2D-1 (real then imag input planes).

__global__ __launch_bounds__(256) void pack_qkv_kernel(
    const float* __restrict__ Wq_r, const float* __restrict__ Wq_i,
    const float* __restrict__ Wk_r, const float* __restrict__ Wk_i,
    const float* __restrict__ Wv_r, const float* __restrict__ Wv_i,
    unsigned short* __restrict__ out) {
    int idx = blockIdx.x * 256 + threadIdx.x;       // L*1536*512
    int l = idx / 786432;
    int rem = idx - l * 786432;
    int n = rem >> 9, k = rem & 511;
    int blk = n >> 8;                                // 0..5 : qr qi kr ki vr vi
    int no = n & 255, kk = k & 255;
    bool khi = (k >= 256);
    bool imag = (blk & 1);
    const float *Wr, *Wi;
    int proj = blk >> 1;
    if (proj == 0)      { Wr = Wq_r; Wi = Wq_i; }
    else if (proj == 1) { Wr = Wk_r; Wi = Wk_i; }
    else                { Wr = Wv_r; Wi = Wv_i; }
    int wi = l * 65536 + kk * 256 + no;
    float val = !imag ? (khi ? -Wi[wi] : Wr[wi])
                      : (khi ?  Wr[wi] : Wi[wi]);
    out[idx] = f2bf(val);
}

__global__ __launch_bounds__(256) void pack_o_kernel(
    const float* __restrict__ Wo_r, const float* __restrict__ Wo_i,
    unsigned short* __restrict__ out) {
    int idx = blockIdx.x * 256 + threadIdx.x;       // L*512*512
    int l = idx >> 18;
    int rem = idx & 262143;
    int n = rem >> 9, k = rem & 511;
    bool imag = (n >= 256);
    int no = n & 255, kk = k & 255;
    bool khi = (k >= 256);
    int wi = l * 65536 + kk * 256 + no;
    float val = !imag ? (khi ? -Wo_i[wi] : Wo_r[wi])
                      : (khi ?  Wo_r[wi] : Wo_i[wi]);
    out[idx] = f2bf(val);
}

__global__ __launch_bounds__(256) void pack_ffn1_kernel(
    const float* __restrict__ W1_r, const float* __restrict__ W1_i,
    unsigned short* __restrict__ out) {
    int idx = blockIdx.x * 256 + threadIdx.x;       // L*2048*512
    int l = idx >> 20;
    int rem = idx & 1048575;
    int n = rem >> 9, k = rem & 511;
    bool imag = (n >= 1024);
    int no = imag ? n - 1024 : n;
    int kk = k & 255;
    bool khi = (k >= 256);
    int wi = l * 262144 + kk * 1024 + no;
    float val = !imag ? (khi ? -W1_i[wi] : W1_r[wi])
                      : (khi ?  W1_r[wi] : W1_i[wi]);
    out[idx] = f2bf(val);
}

__global__ __launch_bounds__(256) void pack_ffn2_kernel(
    const float* __restrict__ W2_r, const float* __restrict__ W2_i,
    unsigned short* __restrict__ out) {
    int idx = blockIdx.x * 256 + threadIdx.x;       // L*512*2048
    int l = idx >> 20;
    int rem = idx & 1048575;
    int n = rem >> 11, k = rem & 2047;
    bool imag = (n >= 256);
    int no = n & 255;
    int kk = k & 1023;
    bool khi = (k >= 1024);
    int wi = l * 262144 + kk * 256 + no;
    float val = !imag ? (khi ? -W2_i[wi] : W2_r[wi])
                      : (khi ?  W2_r[wi] : W2_i[wi]);
    out[idx] = f2bf(val);
}

__global__ __launch_bounds__(256) void pack_bias_kernel(
    const float* __restrict__ b1r, const float* __restrict__ b1i,
    const float* __restrict__ b2r, const float* __restrict__ b2i,
    float* __restrict__ B1, float* __restrict__ B2) {
    int idx = blockIdx.x * 256 + threadIdx.x;       // 4*2048 + 4*512 = 10240
    if (idx < 8192) {
        int l = idx >> 11, n = idx & 2047;
        bool imag = (n >= 1024);
        int no = imag ? n - 1024 : n;
        int bi = l * 1024 + no;
        B1[idx] = imag ? (b1r[bi] + b1i[bi]) : (b1r[bi] - b1i[bi]);
    } else {
        int i2 = idx - 8192;
        int l = i2 >> 9, n = i2 & 511;
        bool imag = (n >= 256);
        int no = n & 255;
        int bi = l * 256 + no;
        B2[i2] = imag ? (b2r[bi] + b2i[bi]) : (b2r[bi] - b2i[bi]);
    }
}

// ----------------------------- rmsnorm -------------------------------------

__global__ __launch_bounds__(256) void rmsnorm_kernel(const float* __restrict__ X,
                                                      const float* __restrict__ scale,
                                                      unsigned short* __restrict__ out) {
    int row = blockIdx.x * 4 + (threadIdx.x >> 6);
    int lane = threadIdx.x & 63;
    const float4* xrow = (const float4*)(X + (size_t)row * LDX);
    float4 xr = xrow[lane];
    float4 xi = xrow[64 + lane];
    float ss = xr.x * xr.x + xr.y * xr.y + xr.z * xr.z + xr.w * xr.w
             + xi.x * xi.x + xi.y * xi.y + xi.z * xi.z + xi.w * xi.w;
#pragma unroll
    for (int m = 1; m < 64; m <<= 1) ss += __shfl_xor(ss, m);
    float inv = 1.0f / sqrtf(ss * (1.0f / 256.0f) + 1e-8f);
    float4 sc = ((const float4*)scale)[lane];
    ushort4 o0, o1;
    o0.x = f2bf(xr.x * inv * sc.x); o0.y = f2bf(xr.y * inv * sc.y);
    o0.z = f2bf(xr.z * inv * sc.z); o0.w = f2bf(xr.w * inv * sc.w);
    o1.x = f2bf(xi.x * inv * sc.x); o1.y = f2bf(xi.y * inv * sc.y);
    o1.z = f2bf(xi.z * inv * sc.z); o1.w = f2bf(xi.w * inv * sc.w);
    ushort4* orow = (ushort4*)(out + (size_t)row * LDX);
    orow[lane] = o0;
    orow[64 + lane] = o1;
}

// ----------------------------- GEMM ----------------------------------------
// C[M,N] = A[M,K](bf16) @ Bt[N,K]^T(bf16).  128x128 tile, BK=64, 4 waves.
// Double-buffered LDS (2x32KB): stage(t+1) issued BEFORE compute(t); the
// __syncthreads() at iteration end drains vmcnt -> next tile landed.  T1
// bijective XCD-chunk swizzle on a linear grid (all grids %8==0): contiguous
// wg (sharing the A-panel) land on one XCD's L2.
// MODE 0: write bf16.  MODE 1: +bias, exact GELU, write bf16.
// MODE 2: +bias(optional), accumulate fp32 into Xres (ld 512).

template <int MODE>
__global__ __launch_bounds__(256) void gemm_kernel(
    const unsigned short* __restrict__ A, const unsigned short* __restrict__ Bt,
    unsigned short* __restrict__ Obf, const float* __restrict__ bias,
    float* __restrict__ Xres, int K, int N, int nTn) {
    __shared__ __align__(16) char smem[65536];
    const int tid = threadIdx.x;
    const int lane = tid & 63;
    const int wave = tid >> 6;
    const int g = lane >> 4;
    const int rl = lane & 15;
    const int wm = wave >> 1, wn = wave & 1;

    // T1: bijective XCD-chunk swizzle (m204 formula), nwg % 8 == 0 everywhere
    const int nwg = gridDim.x;
    const int qs = nwg >> 3;
    const int xcd = blockIdx.x & 7, pos = blockIdx.x >> 3;
    const int wg = xcd * qs + pos;
    const int tM = wg / nTn, tN = wg - tM * nTn;

    const unsigned short* Abase = A + (size_t)tM * 128 * K;
    const unsigned short* Bbase = Bt + (size_t)tN * 128 * K;
    const int NT = K >> 6;

    auto stage = [&](int t, int buf) {
        char* dA = smem + buf * 32768;
        char* dB = dA + 16384;
        const unsigned short* As = Abase + t * 64;
        const unsigned short* Bs = Bbase + t * 64;
#pragma unroll
        for (int it = 0; it < 4; ++it) {
            int s = it * 256 + tid;
            int r = s >> 3, c = (s & 7) ^ (r & 7);
            async16(As + (size_t)r * K + c * 8, dA + (it * 256 + wave * 64) * 16);
            async16(Bs + (size_t)r * K + c * 8, dB + (it * 256 + wave * 64) * 16);
        }
    };

    f32x4 acc[4][4];
#pragma unroll
    for (int i = 0; i < 4; ++i)
#pragma unroll
        for (int j = 0; j < 4; ++j)
#pragma unroll
            for (int v = 0; v < 4; ++v) acc[i][j][v] = 0.0f;

    stage(0, 0);
    asm volatile("s_waitcnt vmcnt(0)" ::: "memory");
    __syncthreads();

    int cur = 0;
    for (int t = 0; t < NT; ++t) {
        if (t + 1 < NT) stage(t + 1, cur ^ 1);     // prefetch overlaps compute
        char* sA = smem + cur * 32768;
        char* sB = sA + 16384;
#pragma unroll
        for (int ks = 0; ks < 2; ++ks) {
            bf16x8 aF[4], bF[4];
#pragma unroll
            for (int fm = 0; fm < 4; ++fm) {
                int r = wm * 64 + fm * 16 + rl;
                int c = ks * 4 + g;
                aF[fm] = *(const bf16x8*)(sA + r * 128 + ((c ^ (r & 7)) << 4));
            }
#pragma unroll
            for (int fn = 0; fn < 4; ++fn) {
                int r = wn * 64 + fn * 16 + rl;
                int c = ks * 4 + g;
                bF[fn] = *(const bf16x8*)(sB + r * 128 + ((c ^ (r & 7)) << 4));
            }
#pragma unroll
            for (int fm = 0; fm < 4; ++fm)
#pragma unroll
                for (int fn = 0; fn < 4; ++fn)
                    acc[fm][fn] = __builtin_amdgcn_mfma_f32_16x16x32_bf16(
                        aF[fm], bF[fn], acc[fm][fn], 0, 0, 0);
        }
        __syncthreads();   // implicit vmcnt/lgkm drain: next tile landed
        cur ^= 1;
    }

#pragma unroll
    for (int fm = 0; fm < 4; ++fm)
#pragma unroll
        for (int fn = 0; fn < 4; ++fn)
#pragma unroll
            for (int v = 0; v < 4; ++v) {
                int row = tM * 128 + wm * 64 + fm * 16 + g * 4 + v;
                int col = tN * 128 + wn * 64 + fn * 16 + rl;
                float val = acc[fm][fn][v];
                if (MODE == 0) {
                    Obf[(size_t)row * N + col] = f2bf(val);
                } else if (MODE == 1) {
                    float x = val + bias[col];
                    float ge = 0.5f * x * (1.0f + erff(x * 0.70710678118654752f));
                    Obf[(size_t)row * N + col] = f2bf(ge);
                } else {
                    float x = val + (bias ? bias[col] : 0.0f);
                    Xres[(size_t)row * LDX + col] += x;
                }
            }
}

// ----------------------------- windowed attention --------------------------
// One block per (window, head, batch).  QKV buffer: [16384][1536] bf16,
// cols: qr qi kr ki vr vi (256 each).  Output: [16384][512] bf16 (or|oi).

#define AT_KOFF 16384
#define AT_VOFF 34816
#define AT_ROFF 52224

__global__ __launch_bounds__(256) void attn_kernel(
    const unsigned short* __restrict__ qkv, const float* __restrict__ relb_g,
    unsigned short* __restrict__ attout) {
    __shared__ __align__(16) char smem[53264];
    const int tid = threadIdx.x;
    const int lane = tid & 63;
    const int wq = tid >> 6;
    const int g = lane >> 4;
    const int rl = lane & 15;
    const int w = blockIdx.x, h = blockIdx.y, b = blockIdx.z;
    const int tok0 = b * 8192 + w * 128;
    float* relb = (float*)(smem + AT_ROFF);

    for (int i = tid; i < 257; i += 256) relb[i] = relb_g[i];

    // stage Qc,Kc [128][64] bf16 (real|imag along K), XOR chunk swizzle
#pragma unroll
    for (int it = 0; it < 4; ++it) {
        int s = it * 256 + tid;
        int r = s >> 3;
        int c = (s & 7) ^ (r & 7);
        int colq = (c < 4) ? (h * 32 + c * 8) : (256 + h * 32 + (c - 4) * 8);
        const unsigned short* rowp = qkv + (size_t)(tok0 + r) * 1536;
        *(float4*)(smem + s * 16) = *(const float4*)(rowp + colq);
        *(float4*)(smem + AT_KOFF + s * 16) = *(const float4*)(rowp + colq + 512);
    }
    // stage Vt [64][136] bf16: Vt[d'][j] ; d' 0..31 = vr, 32..63 = vi
#pragma unroll
    for (int it = 0; it < 4; ++it) {
        int e = it * 256 + tid;
        int j = e >> 3;
        int d0 = (e & 7) * 8;
        int colv = (d0 < 32) ? (1024 + h * 32 + d0) : (1280 + h * 32 + (d0 - 32));
        float4 vv = *(const float4*)(qkv + (size_t)(tok0 + j) * 1536 + colv);
        const unsigned short* u = (const unsigned short*)&vv;
#pragma unroll
        for (int k = 0; k < 8; ++k)
            *(unsigned short*)(smem + AT_VOFF + ((d0 + k) * 136 + j) * 2) = u[k];
    }
    __syncthreads();

    // S = Qc @ Kc^T  (covers qr.kr + qi.ki via K=64)
    f32x4 accS[2][8];
#pragma unroll
    for (int i = 0; i < 2; ++i)
#pragma unroll
        for (int j = 0; j < 8; ++j)
#pragma unroll
            for (int v = 0; v < 4; ++v) accS[i][j][v] = 0.0f;

#pragma unroll
    for (int ks = 0; ks < 2; ++ks) {
        bf16x8 qf[2], kf[8];
        int c = ks * 4 + g;
#pragma unroll
        for (int fm = 0; fm < 2; ++fm) {
            int r = wq * 32 + fm * 16 + rl;
            qf[fm] = *(const bf16x8*)(smem + r * 128 + ((c ^ (r & 7)) << 4));
        }
#pragma unroll
        for (int fn = 0; fn < 8; ++fn) {
            int r = fn * 16 + rl;
            kf[fn] = *(const bf16x8*)(smem + AT_KOFF + r * 128 + ((c ^ (r & 7)) << 4));
        }
#pragma unroll
        for (int fm = 0; fm < 2; ++fm)
#pragma unroll
            for (int fn = 0; fn < 8; ++fn)
                accS[fm][fn] = __builtin_amdgcn_mfma_f32_16x16x32_bf16(
                    qf[fm], kf[fn], accS[fm][fn], 0, 0, 0);
    }

    // softmax (rows live in 16-lane groups)
#pragma unroll
    for (int fm = 0; fm < 2; ++fm)
#pragma unroll
        for (int v = 0; v < 4; ++v) {
            int i = wq * 32 + fm * 16 + g * 4 + v;
            float m = -1e30f;
#pragma unroll
            for (int fn = 0; fn < 8; ++fn) {
                int j = fn * 16 + rl;
                float s = accS[fm][fn][v] * 0.17677669529663687f + relb[j - i + 128];
                accS[fm][fn][v] = s;
                m = fmaxf(m, s);
            }
            m = fmaxf(m, __shfl_xor(m, 1));
            m = fmaxf(m, __shfl_xor(m, 2));
            m = fmaxf(m, __shfl_xor(m, 4));
            m = fmaxf(m, __shfl_xor(m, 8));
            float sum = 0.0f;
#pragma unroll
            for (int fn = 0; fn < 8; ++fn) {
                float p = __expf(accS[fm][fn][v] - m);
                accS[fm][fn][v] = p;
                sum += p;
            }
            sum += __shfl_xor(sum, 1);
            sum += __shfl_xor(sum, 2);
            sum += __shfl_xor(sum, 4);
            sum += __shfl_xor(sum, 8);
            float inv = 1.0f / sum;
#pragma unroll
            for (int fn = 0; fn < 8; ++fn) accS[fm][fn][v] *= inv;
        }

    __syncthreads();   // all Qc/Kc reads done before P overwrites them

    // write P [128][136] bf16 at offset 0
#pragma unroll
    for (int fm = 0; fm < 2; ++fm)
#pragma unroll
        for (int fn = 0; fn < 8; ++fn)
#pragma unroll
            for (int v = 0; v < 4; ++v) {
                int i = wq * 32 + fm * 16 + g * 4 + v;
                int j = fn * 16 + rl;
                ((unsigned short*)smem)[i * 136 + j] = f2bf(accS[fm][fn][v]);
            }
    __syncthreads();

    // O = P @ V   (combined cols: 0..31 = or, 32..63 = oi)
    f32x4 accO[2][4];
#pragma unroll
    for (int i = 0; i < 2; ++i)
#pragma unroll
        for (int j = 0; j < 4; ++j)
#pragma unroll
            for (int v = 0; v < 4; ++v) accO[i][j][v] = 0.0f;

#pragma unroll
    for (int ks = 0; ks < 4; ++ks) {
        bf16x8 pf[2], vf[4];
#pragma unroll
        for (int fm = 0; fm < 2; ++fm) {
            int r = wq * 32 + fm * 16 + rl;
            pf[fm] = *(const bf16x8*)(smem + r * 272 + ks * 64 + g * 16);
        }
#pragma unroll
        for (int fn = 0; fn < 4; ++fn) {
            int n = fn * 16 + rl;
            vf[fn] = *(const bf16x8*)(smem + AT_VOFF + n * 272 + ks * 64 + g * 16);
        }
#pragma unroll
        for (int fm = 0; fm < 2; ++fm)
#pragma unroll
            for (int fn = 0; fn < 4; ++fn)
                accO[fm][fn] = __builtin_amdgcn_mfma_f32_16x16x32_bf16(
                    pf[fm], vf[fn], accO[fm][fn], 0, 0, 0);
    }

#pragma unroll
    for (int fm = 0; fm < 2; ++fm)
#pragma unroll
        for (int fn = 0; fn < 4; ++fn)
#pragma unroll
            for (int v = 0; v < 4; ++v) {
                int i = wq * 32 + fm * 16 + g * 4 + v;
                int dc = fn * 16 + rl;
                int col = (dc < 32) ? (h * 32 + dc) : (256 + h * 32 + (dc - 32));
                attout[(size_t)(tok0 + i) * 512 + col] = f2bf(accO[fm][fn][v]);
            }
}

// ----------------------------- launch --------------------------------------

extern "C" void kernel_launch(void* const* d_in, const int* in_sizes, int n_in,
                              void* d_out, int out_size, void* d_ws, size_t ws_size,
                              hipStream_t stream) {
    const float* x_real = (const float*)d_in[0];
    const float* x_imag = (const float*)d_in[1];
    const float* Wq_r = (const float*)d_in[2];
    const float* Wq_i = (const float*)d_in[3];
    const float* Wk_r = (const float*)d_in[4];
    const float* Wk_i = (const float*)d_in[5];
    const float* Wv_r = (const float*)d_in[6];
    const float* Wv_i = (const float*)d_in[7];
    const float* Wo_r = (const float*)d_in[8];
    const float* Wo_i = (const float*)d_in[9];
    const float* rel_bias = (const float*)d_in[10];
    const float* norm1 = (const float*)d_in[11];
    const float* norm2 = (const float*)d_in[12];
    const float* W1_r = (const float*)d_in[13];
    const float* b1_r = (const float*)d_in[14];
    const float* W1_i = (const float*)d_in[15];
    const float* b1_i = (const float*)d_in[16];
    const float* W2_r = (const float*)d_in[17];
    const float* b2_r = (const float*)d_in[18];
    const float* W2_i = (const float*)d_in[19];
    const float* b2_i = (const float*)d_in[20];

    char* ws = (char*)d_ws;
    float*          X    = (float*)(ws + 0);                    // 32 MB
    unsigned short* NRM  = (unsigned short*)(ws + 33554432);    // 16 MB
    unsigned short* QKVH = (unsigned short*)(ws + 50331648);    // 64 MB (QKV / FFN-H)
    unsigned short* ATTO = (unsigned short*)(ws + 117440512);   // 16 MB
    unsigned short* WQKV = (unsigned short*)(ws + 134217728);   // 6 MB
    unsigned short* WO   = (unsigned short*)(ws + 140509184);   // 2 MB
    unsigned short* W1P  = (unsigned short*)(ws + 142606336);   // 8 MB
    unsigned short* W2P  = (unsigned short*)(ws + 150994944);   // 8 MB
    float*          B1   = (float*)(ws + 159383552);
    float*          B2   = (float*)(ws + 159416320);

    copyin_kernel<<<8192, 256, 0, stream>>>(x_real, x_imag, X);
    pack_qkv_kernel<<<12288, 256, 0, stream>>>(Wq_r, Wq_i, Wk_r, Wk_i, Wv_r, Wv_i, WQKV);
    pack_o_kernel<<<4096, 256, 0, stream>>>(Wo_r, Wo_i, WO);
    pack_ffn1_kernel<<<16384, 256, 0, stream>>>(W1_r, W1_i, W1P);
    pack_ffn2_kernel<<<16384, 256, 0, stream>>>(W2_r, W2_i, W2P);
    pack_bias_kernel<<<40, 256, 0, stream>>>(b1_r, b1_i, b2_r, b2_i, B1, B2);

    for (int l = 0; l < 4; ++l) {
        rmsnorm_kernel<<<4096, 256, 0, stream>>>(X, norm1 + l * 256, NRM);
        gemm_kernel<0><<<1536, 256, 0, stream>>>(
            NRM, WQKV + (size_t)l * 786432, QKVH, nullptr, nullptr, 512, 1536, 12);
        attn_kernel<<<dim3(64, 8, 2), 256, 0, stream>>>(QKVH, rel_bias + l * 257, ATTO);
        gemm_kernel<2><<<512, 256, 0, stream>>>(
            ATTO, WO + (size_t)l * 262144, nullptr, nullptr, X, 512, 512, 4);
        rmsnorm_kernel<<<4096, 256, 0, stream>>>(X, norm2 + l * 256, NRM);
        gemm_kernel<1><<<2048, 256, 0, stream>>>(
            NRM, W1P + (size_t)l * 1048576, QKVH, B1 + l * 2048, nullptr, 512, 2048, 16);
        gemm_kernel<2><<<512, 256, 0, stream>>>(
            QKVH, W2P + (size_t)l * 1048576, nullptr, B2 + l * 512, X, 2048, 512, 4);
    }
    unpack_kernel<<<8192, 256, 0, stream>>>(X, (float*)d_out);
}

// Round 6
// 1051.409 us; speedup vs baseline: 1.2344x; 1.0358x over previous
//
#include <hip/hip_runtime.h>
#include <cstdint>

// ---------------------------------------------------------------------------
// CVTransformer: L=4, D=256, H=8, DH=32, WS=128, FF=1024, B=2, N=8192
// fp32 residual stream X[16384][512]; all matmuls bf16 MFMA GEMMs, K=2D.
// GEMM: BM=256, 8 waves, 2-buffer LDS with counted-vmcnt prefetch (T3+T4):
// tile t+1 loads stay in flight across both barriers; stage(t+2) after
// compute(t).  T1 XCD chunk swizzle, T2 XOR chunk swizzle (0-conflict).
// ---------------------------------------------------------------------------

typedef __bf16 bf16x8 __attribute__((ext_vector_type(8)));
typedef float  f32x4  __attribute__((ext_vector_type(4)));

#define M_TOK 16384
#define LDX   512

__device__ __forceinline__ unsigned short f2bf(float f) {
    union { float f; unsigned int u; } v; v.f = f;
    unsigned int r = v.u + 0x7FFFu + ((v.u >> 16) & 1u);
    return (unsigned short)(r >> 16);
}

__device__ __forceinline__ void async16(const void* g, void* l) {
    __builtin_amdgcn_global_load_lds(
        (const __attribute__((address_space(1))) void*)g,
        (__attribute__((address_space(3))) void*)l, 16, 0, 0);
}

// ----------------------------- elementwise ---------------------------------

__global__ __launch_bounds__(256) void copyin_kernel(const float* __restrict__ xr,
                                                     const float* __restrict__ xi,
                                                     float* __restrict__ X) {
    int idx = blockIdx.x * 256 + threadIdx.x;       // float4 over [16384][128]
    int t = idx >> 7, c4 = idx & 127;
    float4 v = (c4 < 64) ? ((const float4*)xr)[t * 64 + c4]
                         : ((const float4*)xi)[t * 64 + (c4 - 64)];
    ((float4*)X)[idx] = v;
}

__global__ __launch_bounds__(256) void unpack_kernel(const float* __restrict__ X,
                                                     float* __restrict__ out) {
    int idx = blockIdx.x * 256 + threadIdx.x;       // float4 over [2][16384][64]
    int p = idx >> 20;                               // 1048576 f4 per plane
    int rem = idx & 1048575;
    int t = rem >> 6, d4 = rem & 63;
    ((float4*)out)[idx] = ((const float4*)X)[t * 128 + p * 64 + d4];
}

// ----------------------------- weight packing ------------------------------
// Packed layout: Bt[n][k], k = 0..2D-1 (real then imag input planes).

__global__ __launch_bounds__(256) void pack_qkv_kernel(
    const float* __restrict__ Wq_r, const float* __restrict__ Wq_i,
    const float* __restrict__ Wk_r, const float* __restrict__ Wk_i,
    const float* __restrict__ Wv_r, const float* __restrict__ Wv_i,
    unsigned short* __restrict__ out) {
    int idx = blockIdx.x * 256 + threadIdx.x;       // L*1536*512
    int l = idx / 786432;
    int rem = idx - l * 786432;
    int n = rem >> 9, k = rem & 511;
    int blk = n >> 8;                                // 0..5 : qr qi kr ki vr vi
    int no = n & 255, kk = k & 255;
    bool khi = (k >= 256);
    bool imag = (blk & 1);
    const float *Wr, *Wi;
    int proj = blk >> 1;
    if (proj == 0)      { Wr = Wq_r; Wi = Wq_i; }
    else if (proj == 1) { Wr = Wk_r; Wi = Wk_i; }
    else                { Wr = Wv_r; Wi = Wv_i; }
    int wi = l * 65536 + kk * 256 + no;
    float val = !imag ? (khi ? -Wi[wi] : Wr[wi])
                      : (khi ?  Wr[wi] : Wi[wi]);
    out[idx] = f2bf(val);
}

__global__ __launch_bounds__(256) void pack_o_kernel(
    const float* __restrict__ Wo_r, const float* __restrict__ Wo_i,
    unsigned short* __restrict__ out) {
    int idx = blockIdx.x * 256 + threadIdx.x;       // L*512*512
    int l = idx >> 18;
    int rem = idx & 262143;
    int n = rem >> 9, k = rem & 511;
    bool imag = (n >= 256);
    int no = n & 255, kk = k & 255;
    bool khi = (k >= 256);
    int wi = l * 65536 + kk * 256 + no;
    float val = !imag ? (khi ? -Wo_i[wi] : Wo_r[wi])
                      : (khi ?  Wo_r[wi] : Wo_i[wi]);
    out[idx] = f2bf(val);
}

__global__ __launch_bounds__(256) void pack_ffn1_kernel(
    const float* __restrict__ W1_r, const float* __restrict__ W1_i,
    unsigned short* __restrict__ out) {
    int idx = blockIdx.x * 256 + threadIdx.x;       // L*2048*512
    int l = idx >> 20;
    int rem = idx & 1048575;
    int n = rem >> 9, k = rem & 511;
    bool imag = (n >= 1024);
    int no = imag ? n - 1024 : n;
    int kk = k & 255;
    bool khi = (k >= 256);
    int wi = l * 262144 + kk * 1024 + no;
    float val = !imag ? (khi ? -W1_i[wi] : W1_r[wi])
                      : (khi ?  W1_r[wi] : W1_i[wi]);
    out[idx] = f2bf(val);
}

__global__ __launch_bounds__(256) void pack_ffn2_kernel(
    const float* __restrict__ W2_r, const float* __restrict__ W2_i,
    unsigned short* __restrict__ out) {
    int idx = blockIdx.x * 256 + threadIdx.x;       // L*512*2048
    int l = idx >> 20;
    int rem = idx & 1048575;
    int n = rem >> 11, k = rem & 2047;
    bool imag = (n >= 256);
    int no = n & 255;
    int kk = k & 1023;
    bool khi = (k >= 1024);
    int wi = l * 262144 + kk * 256 + no;
    float val = !imag ? (khi ? -W2_i[wi] : W2_r[wi])
                      : (khi ?  W2_r[wi] : W2_i[wi]);
    out[idx] = f2bf(val);
}

__global__ __launch_bounds__(256) void pack_bias_kernel(
    const float* __restrict__ b1r, const float* __restrict__ b1i,
    const float* __restrict__ b2r, const float* __restrict__ b2i,
    float* __restrict__ B1, float* __restrict__ B2) {
    int idx = blockIdx.x * 256 + threadIdx.x;       // 4*2048 + 4*512 = 10240
    if (idx < 8192) {
        int l = idx >> 11, n = idx & 2047;
        bool imag = (n >= 1024);
        int no = imag ? n - 1024 : n;
        int bi = l * 1024 + no;
        B1[idx] = imag ? (b1r[bi] + b1i[bi]) : (b1r[bi] - b1i[bi]);
    } else {
        int i2 = idx - 8192;
        int l = i2 >> 9, n = i2 & 511;
        bool imag = (n >= 256);
        int no = n & 255;
        int bi = l * 256 + no;
        B2[i2] = imag ? (b2r[bi] + b2i[bi]) : (b2r[bi] - b2i[bi]);
    }
}

// ----------------------------- rmsnorm -------------------------------------

__global__ __launch_bounds__(256) void rmsnorm_kernel(const float* __restrict__ X,
                                                      const float* __restrict__ scale,
                                                      unsigned short* __restrict__ out) {
    int row = blockIdx.x * 4 + (threadIdx.x >> 6);
    int lane = threadIdx.x & 63;
    const float4* xrow = (const float4*)(X + (size_t)row * LDX);
    float4 xr = xrow[lane];
    float4 xi = xrow[64 + lane];
    float ss = xr.x * xr.x + xr.y * xr.y + xr.z * xr.z + xr.w * xr.w
             + xi.x * xi.x + xi.y * xi.y + xi.z * xi.z + xi.w * xi.w;
#pragma unroll
    for (int m = 1; m < 64; m <<= 1) ss += __shfl_xor(ss, m);
    float inv = 1.0f / sqrtf(ss * (1.0f / 256.0f) + 1e-8f);
    float4 sc = ((const float4*)scale)[lane];
    ushort4 o0, o1;
    o0.x = f2bf(xr.x * inv * sc.x); o0.y = f2bf(xr.y * inv * sc.y);
    o0.z = f2bf(xr.z * inv * sc.z); o0.w = f2bf(xr.w * inv * sc.w);
    o1.x = f2bf(xi.x * inv * sc.x); o1.y = f2bf(xi.y * inv * sc.y);
    o1.z = f2bf(xi.z * inv * sc.z); o1.w = f2bf(xi.w * inv * sc.w);
    ushort4* orow = (ushort4*)(out + (size_t)row * LDX);
    orow[lane] = o0;
    orow[64 + lane] = o1;
}

// ----------------------------- GEMM ----------------------------------------
// C[M,N] = A[M,K](bf16) @ Bt[N,K]^T(bf16).  BM=256, BN=256|128, BK=64,
// 8 waves (512 thr).  Wave tile: 64 rows (wm=wave&3) x BN/2 cols (wn=wave>>2).
// 2 LDS buffers of (256+BN)*128 B.  Loop: vmcnt(LPT) [tile t landed, t+1
// still in flight] -> barrier -> compute(t) -> barrier -> stage(t+2, buf t&1).
// Counted vmcnt is the point: never drain to 0 in the main loop (T4).
// MODE 0: bf16 out. 1: +bias, exact GELU, bf16. 2: +bias(opt), fp32 += X.

template <int BN, int MODE>
__global__ __launch_bounds__(512, 2) void gemm2_kernel(
    const unsigned short* __restrict__ A, const unsigned short* __restrict__ Bt,
    unsigned short* __restrict__ Obf, const float* __restrict__ bias,
    float* __restrict__ Xres, int K, int N, int nTn) {
    constexpr int FN = BN / 32;            // B frags per wave (cols = FN*16)
    constexpr int LB = BN / 64;            // B loads per thread per stage
    constexpr int BUFSZ = (256 + BN) * 128;
    __shared__ __align__(16) char smem[2 * BUFSZ];
    const int tid = threadIdx.x;
    const int lane = tid & 63;
    const int wave = tid >> 6;
    const int g = lane >> 4, rl = lane & 15;
    const int wm = wave & 3, wn = wave >> 2;

    // T1: bijective XCD-chunk swizzle (nwg % 8 == 0 for every launch)
    const int nwg = gridDim.x;
    const int qs = nwg >> 3;
    const int wg = (blockIdx.x & 7) * qs + (blockIdx.x >> 3);
    const int tM = wg / nTn, tN = wg - tM * nTn;

    const unsigned short* Abase = A + (size_t)tM * 256 * K;
    const unsigned short* Bbase = Bt + (size_t)tN * BN * K;
    const int NT = K >> 6;

    auto stage = [&](int t, int buf) {
        char* dA = smem + buf * BUFSZ;
        char* dB = dA + 32768;
        const unsigned short* As = Abase + t * 64;
        const unsigned short* Bs = Bbase + t * 64;
#pragma unroll
        for (int it = 0; it < 4; ++it) {
            int s = it * 512 + tid;
            int r = s >> 3, c = (s & 7) ^ (r & 7);
            async16(As + (size_t)r * K + c * 8, dA + (it * 512 + wave * 64) * 16);
        }
#pragma unroll
        for (int it = 0; it < LB; ++it) {
            int s = it * 512 + tid;
            int r = s >> 3, c = (s & 7) ^ (r & 7);
            async16(Bs + (size_t)r * K + c * 8, dB + (it * 512 + wave * 64) * 16);
        }
    };

    f32x4 acc[4][FN];
#pragma unroll
    for (int i = 0; i < 4; ++i)
#pragma unroll
        for (int j = 0; j < FN; ++j)
#pragma unroll
            for (int v = 0; v < 4; ++v) acc[i][j][v] = 0.0f;

    stage(0, 0);
    stage(1, 1);

    int cur = 0;
    for (int t = 0; t < NT; ++t) {
        if (t + 1 < NT) {
            if constexpr (BN == 256) asm volatile("s_waitcnt vmcnt(8)" ::: "memory");
            else                     asm volatile("s_waitcnt vmcnt(6)" ::: "memory");
        } else {
            asm volatile("s_waitcnt vmcnt(0)" ::: "memory");
        }
        __builtin_amdgcn_s_barrier();
        char* sA = smem + cur * BUFSZ;
        char* sB = sA + 32768;
#pragma unroll
        for (int ks = 0; ks < 2; ++ks) {
            bf16x8 aF[4], bF[FN];
            int c = ks * 4 + g;
#pragma unroll
            for (int fm = 0; fm < 4; ++fm) {
                int hr = wm * 64 + fm * 16 + rl;
                aF[fm] = *(const bf16x8*)(sA + hr * 128 + ((c ^ (hr & 7)) << 4));
            }
#pragma unroll
            for (int fn = 0; fn < FN; ++fn) {
                int hr = wn * (BN / 2) + fn * 16 + rl;
                bF[fn] = *(const bf16x8*)(sB + hr * 128 + ((c ^ (hr & 7)) << 4));
            }
#pragma unroll
            for (int fm = 0; fm < 4; ++fm)
#pragma unroll
                for (int fn = 0; fn < FN; ++fn)
                    acc[fm][fn] = __builtin_amdgcn_mfma_f32_16x16x32_bf16(
                        aF[fm], bF[fn], acc[fm][fn], 0, 0, 0);
        }
        __builtin_amdgcn_s_barrier();
        if (t + 2 < NT) stage(t + 2, cur);
        cur ^= 1;
    }

#pragma unroll
    for (int fm = 0; fm < 4; ++fm)
#pragma unroll
        for (int fn = 0; fn < FN; ++fn)
#pragma unroll
            for (int v = 0; v < 4; ++v) {
                int row = tM * 256 + wm * 64 + fm * 16 + g * 4 + v;
                int col = tN * BN + wn * (BN / 2) + fn * 16 + rl;
                float val = acc[fm][fn][v];
                if (MODE == 0) {
                    Obf[(size_t)row * N + col] = f2bf(val);
                } else if (MODE == 1) {
                    float x = val + bias[col];
                    float ge = 0.5f * x * (1.0f + erff(x * 0.70710678118654752f));
                    Obf[(size_t)row * N + col] = f2bf(ge);
                } else {
                    float x = val + (bias ? bias[col] : 0.0f);
                    Xres[(size_t)row * LDX + col] += x;
                }
            }
}

// ----------------------------- windowed attention --------------------------
// One block per (window, head, batch).  QKV buffer: [16384][1536] bf16,
// cols: qr qi kr ki vr vi (256 each).  Output: [16384][512] bf16 (or|oi).

#define AT_KOFF 16384
#define AT_VOFF 34816
#define AT_ROFF 52224

__global__ __launch_bounds__(256) void attn_kernel(
    const unsigned short* __restrict__ qkv, const float* __restrict__ relb_g,
    unsigned short* __restrict__ attout) {
    __shared__ __align__(16) char smem[53264];
    const int tid = threadIdx.x;
    const int lane = tid & 63;
    const int wq = tid >> 6;
    const int g = lane >> 4;
    const int rl = lane & 15;
    const int w = blockIdx.x, h = blockIdx.y, b = blockIdx.z;
    const int tok0 = b * 8192 + w * 128;
    float* relb = (float*)(smem + AT_ROFF);

    for (int i = tid; i < 257; i += 256) relb[i] = relb_g[i];

    // stage Qc,Kc [128][64] bf16 (real|imag along K), XOR chunk swizzle
#pragma unroll
    for (int it = 0; it < 4; ++it) {
        int s = it * 256 + tid;
        int r = s >> 3;
        int c = (s & 7) ^ (r & 7);
        int colq = (c < 4) ? (h * 32 + c * 8) : (256 + h * 32 + (c - 4) * 8);
        const unsigned short* rowp = qkv + (size_t)(tok0 + r) * 1536;
        *(float4*)(smem + s * 16) = *(const float4*)(rowp + colq);
        *(float4*)(smem + AT_KOFF + s * 16) = *(const float4*)(rowp + colq + 512);
    }
    // stage Vt [64][136] bf16: Vt[d'][j] ; d' 0..31 = vr, 32..63 = vi
#pragma unroll
    for (int it = 0; it < 4; ++it) {
        int e = it * 256 + tid;
        int j = e >> 3;
        int d0 = (e & 7) * 8;
        int colv = (d0 < 32) ? (1024 + h * 32 + d0) : (1280 + h * 32 + (d0 - 32));
        float4 vv = *(const float4*)(qkv + (size_t)(tok0 + j) * 1536 + colv);
        const unsigned short* u = (const unsigned short*)&vv;
#pragma unroll
        for (int k = 0; k < 8; ++k)
            *(unsigned short*)(smem + AT_VOFF + ((d0 + k) * 136 + j) * 2) = u[k];
    }
    __syncthreads();

    // S = Qc @ Kc^T  (covers qr.kr + qi.ki via K=64)
    f32x4 accS[2][8];
#pragma unroll
    for (int i = 0; i < 2; ++i)
#pragma unroll
        for (int j = 0; j < 8; ++j)
#pragma unroll
            for (int v = 0; v < 4; ++v) accS[i][j][v] = 0.0f;

#pragma unroll
    for (int ks = 0; ks < 2; ++ks) {
        bf16x8 qf[2], kf[8];
        int c = ks * 4 + g;
#pragma unroll
        for (int fm = 0; fm < 2; ++fm) {
            int r = wq * 32 + fm * 16 + rl;
            qf[fm] = *(const bf16x8*)(smem + r * 128 + ((c ^ (r & 7)) << 4));
        }
#pragma unroll
        for (int fn = 0; fn < 8; ++fn) {
            int r = fn * 16 + rl;
            kf[fn] = *(const bf16x8*)(smem + AT_KOFF + r * 128 + ((c ^ (r & 7)) << 4));
        }
#pragma unroll
        for (int fm = 0; fm < 2; ++fm)
#pragma unroll
            for (int fn = 0; fn < 8; ++fn)
                accS[fm][fn] = __builtin_amdgcn_mfma_f32_16x16x32_bf16(
                    qf[fm], kf[fn], accS[fm][fn], 0, 0, 0);
    }

    // softmax (rows live in 16-lane groups)
#pragma unroll
    for (int fm = 0; fm < 2; ++fm)
#pragma unroll
        for (int v = 0; v < 4; ++v) {
            int i = wq * 32 + fm * 16 + g * 4 + v;
            float m = -1e30f;
#pragma unroll
            for (int fn = 0; fn < 8; ++fn) {
                int j = fn * 16 + rl;
                float s = accS[fm][fn][v] * 0.17677669529663687f + relb[j - i + 128];
                accS[fm][fn][v] = s;
                m = fmaxf(m, s);
            }
            m = fmaxf(m, __shfl_xor(m, 1));
            m = fmaxf(m, __shfl_xor(m, 2));
            m = fmaxf(m, __shfl_xor(m, 4));
            m = fmaxf(m, __shfl_xor(m, 8));
            float sum = 0.0f;
#pragma unroll
            for (int fn = 0; fn < 8; ++fn) {
                float p = __expf(accS[fm][fn][v] - m);
                accS[fm][fn][v] = p;
                sum += p;
            }
            sum += __shfl_xor(sum, 1);
            sum += __shfl_xor(sum, 2);
            sum += __shfl_xor(sum, 4);
            sum += __shfl_xor(sum, 8);
            float inv = 1.0f / sum;
#pragma unroll
            for (int fn = 0; fn < 8; ++fn) accS[fm][fn][v] *= inv;
        }

    __syncthreads();   // all Qc/Kc reads done before P overwrites them

    // write P [128][136] bf16 at offset 0
#pragma unroll
    for (int fm = 0; fm < 2; ++fm)
#pragma unroll
        for (int fn = 0; fn < 8; ++fn)
#pragma unroll
            for (int v = 0; v < 4; ++v) {
                int i = wq * 32 + fm * 16 + g * 4 + v;
                int j = fn * 16 + rl;
                ((unsigned short*)smem)[i * 136 + j] = f2bf(accS[fm][fn][v]);
            }
    __syncthreads();

    // O = P @ V   (combined cols: 0..31 = or, 32..63 = oi)
    f32x4 accO[2][4];
#pragma unroll
    for (int i = 0; i < 2; ++i)
#pragma unroll
        for (int j = 0; j < 4; ++j)
#pragma unroll
            for (int v = 0; v < 4; ++v) accO[i][j][v] = 0.0f;

#pragma unroll
    for (int ks = 0; ks < 4; ++ks) {
        bf16x8 pf[2], vf[4];
#pragma unroll
        for (int fm = 0; fm < 2; ++fm) {
            int r = wq * 32 + fm * 16 + rl;
            pf[fm] = *(const bf16x8*)(smem + r * 272 + ks * 64 + g * 16);
        }
#pragma unroll
        for (int fn = 0; fn < 4; ++fn) {
            int n = fn * 16 + rl;
            vf[fn] = *(const bf16x8*)(smem + AT_VOFF + n * 272 + ks * 64 + g * 16);
        }
#pragma unroll
        for (int fm = 0; fm < 2; ++fm)
#pragma unroll
            for (int fn = 0; fn < 4; ++fn)
                accO[fm][fn] = __builtin_amdgcn_mfma_f32_16x16x32_bf16(
                    pf[fm], vf[fn], accO[fm][fn], 0, 0, 0);
    }

#pragma unroll
    for (int fm = 0; fm < 2; ++fm)
#pragma unroll
        for (int fn = 0; fn < 4; ++fn)
#pragma unroll
            for (int v = 0; v < 4; ++v) {
                int i = wq * 32 + fm * 16 + g * 4 + v;
                int dc = fn * 16 + rl;
                int col = (dc < 32) ? (h * 32 + dc) : (256 + h * 32 + (dc - 32));
                attout[(size_t)(tok0 + i) * 512 + col] = f2bf(accO[fm][fn][v]);
            }
}

// ----------------------------- launch --------------------------------------

extern "C" void kernel_launch(void* const* d_in, const int* in_sizes, int n_in,
                              void* d_out, int out_size, void* d_ws, size_t ws_size,
                              hipStream_t stream) {
    const float* x_real = (const float*)d_in[0];
    const float* x_imag = (const float*)d_in[1];
    const float* Wq_r = (const float*)d_in[2];
    const float* Wq_i = (const float*)d_in[3];
    const float* Wk_r = (const float*)d_in[4];
    const float* Wk_i = (const float*)d_in[5];
    const float* Wv_r = (const float*)d_in[6];
    const float* Wv_i = (const float*)d_in[7];
    const float* Wo_r = (const float*)d_in[8];
    const float* Wo_i = (const float*)d_in[9];
    const float* rel_bias = (const float*)d_in[10];
    const float* norm1 = (const float*)d_in[11];
    const float* norm2 = (const float*)d_in[12];
    const float* W1_r = (const float*)d_in[13];
    const float* b1_r = (const float*)d_in[14];
    const float* W1_i = (const float*)d_in[15];
    const float* b1_i = (const float*)d_in[16];
    const float* W2_r = (const float*)d_in[17];
    const float* b2_r = (const float*)d_in[18];
    const float* W2_i = (const float*)d_in[19];
    const float* b2_i = (const float*)d_in[20];

    char* ws = (char*)d_ws;
    float*          X    = (float*)(ws + 0);                    // 32 MB
    unsigned short* NRM  = (unsigned short*)(ws + 33554432);    // 16 MB
    unsigned short* QKVH = (unsigned short*)(ws + 50331648);    // 64 MB (QKV / FFN-H)
    unsigned short* ATTO = (unsigned short*)(ws + 117440512);   // 16 MB
    unsigned short* WQKV = (unsigned short*)(ws + 134217728);   // 6 MB
    unsigned short* WO   = (unsigned short*)(ws + 140509184);   // 2 MB
    unsigned short* W1P  = (unsigned short*)(ws + 142606336);   // 8 MB
    unsigned short* W2P  = (unsigned short*)(ws + 150994944);   // 8 MB
    float*          B1   = (float*)(ws + 159383552);
    float*          B2   = (float*)(ws + 159416320);

    copyin_kernel<<<8192, 256, 0, stream>>>(x_real, x_imag, X);
    pack_qkv_kernel<<<12288, 256, 0, stream>>>(Wq_r, Wq_i, Wk_r, Wk_i, Wv_r, Wv_i, WQKV);
    pack_o_kernel<<<4096, 256, 0, stream>>>(Wo_r, Wo_i, WO);
    pack_ffn1_kernel<<<16384, 256, 0, stream>>>(W1_r, W1_i, W1P);
    pack_ffn2_kernel<<<16384, 256, 0, stream>>>(W2_r, W2_i, W2P);
    pack_bias_kernel<<<40, 256, 0, stream>>>(b1_r, b1_i, b2_r, b2_i, B1, B2);

    for (int l = 0; l < 4; ++l) {
        rmsnorm_kernel<<<4096, 256, 0, stream>>>(X, norm1 + l * 256, NRM);
        gemm2_kernel<128, 0><<<768, 512, 0, stream>>>(
            NRM, WQKV + (size_t)l * 786432, QKVH, nullptr, nullptr, 512, 1536, 12);
        attn_kernel<<<dim3(64, 8, 2), 256, 0, stream>>>(QKVH, rel_bias + l * 257, ATTO);
        gemm2_kernel<128, 2><<<256, 512, 0, stream>>>(
            ATTO, WO + (size_t)l * 262144, nullptr, nullptr, X, 512, 512, 4);
        rmsnorm_kernel<<<4096, 256, 0, stream>>>(X, norm2 + l * 256, NRM);
        gemm2_kernel<256, 1><<<512, 512, 0, stream>>>(
            NRM, W1P + (size_t)l * 1048576, QKVH, B1 + l * 2048, nullptr, 512, 2048, 8);
        gemm2_kernel<128, 2><<<256, 512, 0, stream>>>(
            QKVH, W2P + (size_t)l * 1048576, nullptr, B2 + l * 512, X, 2048, 512, 4);
    }
    unpack_kernel<<<8192, 256, 0, stream>>>(X, (float*)d_out);
}

// Round 7
// 1038.474 us; speedup vs baseline: 1.2498x; 1.0125x over previous
//
#include <hip/hip_runtime.h>
#include <cstdint>

// ---------------------------------------------------------------------------
// CVTransformer: L=4, D=256, H=8, DH=32, WS=128, FF=1024, B=2, N=8192
// Residual stream X = d_out, planar fp32 [2][16384][256] (real, imag planes).
// All matmuls bf16 MFMA GEMMs with K = 2*D (real|imag along K in A/NRM).
// GEMM: BM=BN=128, 4 waves, 2x32KB LDS dbuf -> 2 blocks/CU, counted-vmcnt(8)
// cross-barrier prefetch (stage t+2 after compute t).  T1 XCD chunk swizzle,
// T2 XOR chunk swizzle (0-conflict, verified bank-conflict-free).
// ---------------------------------------------------------------------------

typedef __bf16 bf16x8 __attribute__((ext_vector_type(8)));
typedef float  f32x4  __attribute__((ext_vector_type(4)));

#define M_TOK 16384
#define PLANE 4194304   // 16384*256 floats per plane

__device__ __forceinline__ unsigned short f2bf(float f) {
    union { float f; unsigned int u; } v; v.f = f;
    unsigned int r = v.u + 0x7FFFu + ((v.u >> 16) & 1u);
    return (unsigned short)(r >> 16);
}

__device__ __forceinline__ void async16(const void* g, void* l) {
    __builtin_amdgcn_global_load_lds(
        (const __attribute__((address_space(1))) void*)g,
        (__attribute__((address_space(3))) void*)l, 16, 0, 0);
}

// ----------------------------- elementwise ---------------------------------
// copy x_real -> plane0, x_imag -> plane1 of X (= d_out)

__global__ __launch_bounds__(256) void copyin_kernel(const float* __restrict__ xr,
                                                     const float* __restrict__ xi,
                                                     float* __restrict__ X) {
    int idx = blockIdx.x * 256 + threadIdx.x;       // float4 over [2][16384][64]
    int p = idx >> 20;                               // 1048576 f4 per plane
    int rem = idx & 1048575;
    ((float4*)X)[idx] = p ? ((const float4*)xi)[rem] : ((const float4*)xr)[rem];
}

// ----------------------------- weight packing ------------------------------
// Packed layout: Bt[n][k], k = 0..2D-1 (real then imag input planes).

__global__ __launch_bounds__(256) void pack_qkv_kernel(
    const float* __restrict__ Wq_r, const float* __restrict__ Wq_i,
    const float* __restrict__ Wk_r, const float* __restrict__ Wk_i,
    const float* __restrict__ Wv_r, const float* __restrict__ Wv_i,
    unsigned short* __restrict__ out) {
    int idx = blockIdx.x * 256 + threadIdx.x;       // L*1536*512
    int l = idx / 786432;
    int rem = idx - l * 786432;
    int n = rem >> 9, k = rem & 511;
    int blk = n >> 8;                                // 0..5 : qr qi kr ki vr vi
    int no = n & 255, kk = k & 255;
    bool khi = (k >= 256);
    bool imag = (blk & 1);
    const float *Wr, *Wi;
    int proj = blk >> 1;
    if (proj == 0)      { Wr = Wq_r; Wi = Wq_i; }
    else if (proj == 1) { Wr = Wk_r; Wi = Wk_i; }
    else                { Wr = Wv_r; Wi = Wv_i; }
    int wi = l * 65536 + kk * 256 + no;
    float val = !imag ? (khi ? -Wi[wi] : Wr[wi])
                      : (khi ?  Wr[wi] : Wi[wi]);
    out[idx] = f2bf(val);
}

__global__ __launch_bounds__(256) void pack_o_kernel(
    const float* __restrict__ Wo_r, const float* __restrict__ Wo_i,
    unsigned short* __restrict__ out) {
    int idx = blockIdx.x * 256 + threadIdx.x;       // L*512*512
    int l = idx >> 18;
    int rem = idx & 262143;
    int n = rem >> 9, k = rem & 511;
    bool imag = (n >= 256);
    int no = n & 255, kk = k & 255;
    bool khi = (k >= 256);
    int wi = l * 65536 + kk * 256 + no;
    float val = !imag ? (khi ? -Wo_i[wi] : Wo_r[wi])
                      : (khi ?  Wo_r[wi] : Wo_i[wi]);
    out[idx] = f2bf(val);
}

__global__ __launch_bounds__(256) void pack_ffn1_kernel(
    const float* __restrict__ W1_r, const float* __restrict__ W1_i,
    unsigned short* __restrict__ out) {
    int idx = blockIdx.x * 256 + threadIdx.x;       // L*2048*512
    int l = idx >> 20;
    int rem = idx & 1048575;
    int n = rem >> 9, k = rem & 511;
    bool imag = (n >= 1024);
    int no = imag ? n - 1024 : n;
    int kk = k & 255;
    bool khi = (k >= 256);
    int wi = l * 262144 + kk * 1024 + no;
    float val = !imag ? (khi ? -W1_i[wi] : W1_r[wi])
                      : (khi ?  W1_r[wi] : W1_i[wi]);
    out[idx] = f2bf(val);
}

__global__ __launch_bounds__(256) void pack_ffn2_kernel(
    const float* __restrict__ W2_r, const float* __restrict__ W2_i,
    unsigned short* __restrict__ out) {
    int idx = blockIdx.x * 256 + threadIdx.x;       // L*512*2048
    int l = idx >> 20;
    int rem = idx & 1048575;
    int n = rem >> 11, k = rem & 2047;
    bool imag = (n >= 256);
    int no = n & 255;
    int kk = k & 1023;
    bool khi = (k >= 1024);
    int wi = l * 262144 + kk * 256 + no;
    float val = !imag ? (khi ? -W2_i[wi] : W2_r[wi])
                      : (khi ?  W2_r[wi] : W2_i[wi]);
    out[idx] = f2bf(val);
}

__global__ __launch_bounds__(256) void pack_bias_kernel(
    const float* __restrict__ b1r, const float* __restrict__ b1i,
    const float* __restrict__ b2r, const float* __restrict__ b2i,
    float* __restrict__ B1, float* __restrict__ B2) {
    int idx = blockIdx.x * 256 + threadIdx.x;       // 4*2048 + 4*512 = 10240
    if (idx < 8192) {
        int l = idx >> 11, n = idx & 2047;
        bool imag = (n >= 1024);
        int no = imag ? n - 1024 : n;
        int bi = l * 1024 + no;
        B1[idx] = imag ? (b1r[bi] + b1i[bi]) : (b1r[bi] - b1i[bi]);
    } else {
        int i2 = idx - 8192;
        int l = i2 >> 9, n = i2 & 511;
        bool imag = (n >= 256);
        int no = n & 255;
        int bi = l * 256 + no;
        B2[i2] = imag ? (b2r[bi] + b2i[bi]) : (b2r[bi] - b2i[bi]);
    }
}

// ----------------------------- rmsnorm -------------------------------------
// reads planar X (plane0 = real, plane1 = imag), writes NRM[16384][512] bf16

__global__ __launch_bounds__(256) void rmsnorm_kernel(const float* __restrict__ X,
                                                      const float* __restrict__ scale,
                                                      unsigned short* __restrict__ out) {
    int row = blockIdx.x * 4 + (threadIdx.x >> 6);
    int lane = threadIdx.x & 63;
    float4 xr = ((const float4*)(X + (size_t)row * 256))[lane];
    float4 xi = ((const float4*)(X + PLANE + (size_t)row * 256))[lane];
    float ss = xr.x * xr.x + xr.y * xr.y + xr.z * xr.z + xr.w * xr.w
             + xi.x * xi.x + xi.y * xi.y + xi.z * xi.z + xi.w * xi.w;
#pragma unroll
    for (int m = 1; m < 64; m <<= 1) ss += __shfl_xor(ss, m);
    float inv = 1.0f / sqrtf(ss * (1.0f / 256.0f) + 1e-8f);
    float4 sc = ((const float4*)scale)[lane];
    ushort4 o0, o1;
    o0.x = f2bf(xr.x * inv * sc.x); o0.y = f2bf(xr.y * inv * sc.y);
    o0.z = f2bf(xr.z * inv * sc.z); o0.w = f2bf(xr.w * inv * sc.w);
    o1.x = f2bf(xi.x * inv * sc.x); o1.y = f2bf(xi.y * inv * sc.y);
    o1.z = f2bf(xi.z * inv * sc.z); o1.w = f2bf(xi.w * inv * sc.w);
    ushort4* orow = (ushort4*)(out + (size_t)row * 512);
    orow[lane] = o0;
    orow[64 + lane] = o1;
}

// ----------------------------- GEMM ----------------------------------------
// C[M,N] = A[M,K](bf16) @ Bt[N,K]^T(bf16).  BM=BN=128, BK=64, 4 waves,
// 2 x 32KB LDS buffers -> 2 blocks/CU.  Pipeline per iter t:
//   vmcnt(8)   [stage(t) landed; stage(t+1)'s 8 loads still in flight]
//   barrier -> ds_read frags + 32 MFMA -> barrier -> stage(t+2, buf t&1)
// Counted vmcnt: never drain to 0 in the main loop (T4).
// MODE 0: bf16 out. 1: +bias, exact GELU, bf16. 2: +bias(opt), fp32 += planar X.

template <int MODE>
__global__ __launch_bounds__(256, 2) void gemm3_kernel(
    const unsigned short* __restrict__ A, const unsigned short* __restrict__ Bt,
    unsigned short* __restrict__ Obf, const float* __restrict__ bias,
    float* __restrict__ Xres, int K, int N, int nTn) {
    __shared__ __align__(16) char smem[65536];
    const int tid = threadIdx.x;
    const int lane = tid & 63;
    const int wave = tid >> 6;
    const int g = lane >> 4, rl = lane & 15;
    const int wm = wave >> 1, wn = wave & 1;

    // T1: bijective XCD-chunk swizzle (nwg % 8 == 0 for every launch)
    const int nwg = gridDim.x;
    const int qs = nwg >> 3;
    const int wg = (blockIdx.x & 7) * qs + (blockIdx.x >> 3);
    const int tM = wg / nTn, tN = wg - tM * nTn;

    const unsigned short* Abase = A + (size_t)tM * 128 * K;
    const unsigned short* Bbase = Bt + (size_t)tN * 128 * K;
    const int NT = K >> 6;

    auto stage = [&](int t, int buf) {
        char* dA = smem + buf * 32768;
        char* dB = dA + 16384;
        const unsigned short* As = Abase + t * 64;
        const unsigned short* Bs = Bbase + t * 64;
#pragma unroll
        for (int it = 0; it < 4; ++it) {
            int s = it * 256 + tid;
            int r = s >> 3, c = (s & 7) ^ (r & 7);
            async16(As + (size_t)r * K + c * 8, dA + (it * 256 + wave * 64) * 16);
            async16(Bs + (size_t)r * K + c * 8, dB + (it * 256 + wave * 64) * 16);
        }
    };

    f32x4 acc[4][4];
#pragma unroll
    for (int i = 0; i < 4; ++i)
#pragma unroll
        for (int j = 0; j < 4; ++j)
#pragma unroll
            for (int v = 0; v < 4; ++v) acc[i][j][v] = 0.0f;

    stage(0, 0);
    stage(1, 1);

    int cur = 0;
    for (int t = 0; t < NT; ++t) {
        if (t + 1 < NT) asm volatile("s_waitcnt vmcnt(8)" ::: "memory");
        else            asm volatile("s_waitcnt vmcnt(0)" ::: "memory");
        __builtin_amdgcn_s_barrier();
        char* sA = smem + cur * 32768;
        char* sB = sA + 16384;
#pragma unroll
        for (int ks = 0; ks < 2; ++ks) {
            bf16x8 aF[4], bF[4];
            int c = ks * 4 + g;
#pragma unroll
            for (int fm = 0; fm < 4; ++fm) {
                int hr = wm * 64 + fm * 16 + rl;
                aF[fm] = *(const bf16x8*)(sA + hr * 128 + ((c ^ (hr & 7)) << 4));
            }
#pragma unroll
            for (int fn = 0; fn < 4; ++fn) {
                int hr = wn * 64 + fn * 16 + rl;
                bF[fn] = *(const bf16x8*)(sB + hr * 128 + ((c ^ (hr & 7)) << 4));
            }
#pragma unroll
            for (int fm = 0; fm < 4; ++fm)
#pragma unroll
                for (int fn = 0; fn < 4; ++fn)
                    acc[fm][fn] = __builtin_amdgcn_mfma_f32_16x16x32_bf16(
                        aF[fm], bF[fn], acc[fm][fn], 0, 0, 0);
        }
        __builtin_amdgcn_s_barrier();
        if (t + 2 < NT) stage(t + 2, cur);
        cur ^= 1;
    }

#pragma unroll
    for (int fm = 0; fm < 4; ++fm)
#pragma unroll
        for (int fn = 0; fn < 4; ++fn)
#pragma unroll
            for (int v = 0; v < 4; ++v) {
                int row = tM * 128 + wm * 64 + fm * 16 + g * 4 + v;
                int col = tN * 128 + wn * 64 + fn * 16 + rl;
                float val = acc[fm][fn][v];
                if (MODE == 0) {
                    Obf[(size_t)row * N + col] = f2bf(val);
                } else if (MODE == 1) {
                    float x = val + bias[col];
                    float ge = 0.5f * x * (1.0f + erff(x * 0.70710678118654752f));
                    Obf[(size_t)row * N + col] = f2bf(ge);
                } else {
                    float x = val + (bias ? bias[col] : 0.0f);
                    // planar residual: col<256 -> plane0(real), else plane1(imag)
                    size_t off = (col < 256 ? 0 : (size_t)PLANE)
                               + (size_t)row * 256 + (col & 255);
                    Xres[off] += x;
                }
            }
}

// ----------------------------- windowed attention --------------------------
// One block per (window, head, batch).  QKV buffer: [16384][1536] bf16,
// cols: qr qi kr ki vr vi (256 each).  Output: [16384][512] bf16 (or|oi).

#define AT_KOFF 16384
#define AT_VOFF 34816
#define AT_ROFF 52224

__global__ __launch_bounds__(256) void attn_kernel(
    const unsigned short* __restrict__ qkv, const float* __restrict__ relb_g,
    unsigned short* __restrict__ attout) {
    __shared__ __align__(16) char smem[53264];
    const int tid = threadIdx.x;
    const int lane = tid & 63;
    const int wq = tid >> 6;
    const int g = lane >> 4;
    const int rl = lane & 15;
    const int w = blockIdx.x, h = blockIdx.y, b = blockIdx.z;
    const int tok0 = b * 8192 + w * 128;
    float* relb = (float*)(smem + AT_ROFF);

    for (int i = tid; i < 257; i += 256) relb[i] = relb_g[i];

    // stage Qc,Kc [128][64] bf16 (real|imag along K), XOR chunk swizzle
#pragma unroll
    for (int it = 0; it < 4; ++it) {
        int s = it * 256 + tid;
        int r = s >> 3;
        int c = (s & 7) ^ (r & 7);
        int colq = (c < 4) ? (h * 32 + c * 8) : (256 + h * 32 + (c - 4) * 8);
        const unsigned short* rowp = qkv + (size_t)(tok0 + r) * 1536;
        *(float4*)(smem + s * 16) = *(const float4*)(rowp + colq);
        *(float4*)(smem + AT_KOFF + s * 16) = *(const float4*)(rowp + colq + 512);
    }
    // stage Vt [64][136] bf16: Vt[d'][j] ; d' 0..31 = vr, 32..63 = vi
#pragma unroll
    for (int it = 0; it < 4; ++it) {
        int e = it * 256 + tid;
        int j = e >> 3;
        int d0 = (e & 7) * 8;
        int colv = (d0 < 32) ? (1024 + h * 32 + d0) : (1280 + h * 32 + (d0 - 32));
        float4 vv = *(const float4*)(qkv + (size_t)(tok0 + j) * 1536 + colv);
        const unsigned short* u = (const unsigned short*)&vv;
#pragma unroll
        for (int k = 0; k < 8; ++k)
            *(unsigned short*)(smem + AT_VOFF + ((d0 + k) * 136 + j) * 2) = u[k];
    }
    __syncthreads();

    // S = Qc @ Kc^T  (covers qr.kr + qi.ki via K=64)
    f32x4 accS[2][8];
#pragma unroll
    for (int i = 0; i < 2; ++i)
#pragma unroll
        for (int j = 0; j < 8; ++j)
#pragma unroll
            for (int v = 0; v < 4; ++v) accS[i][j][v] = 0.0f;

#pragma unroll
    for (int ks = 0; ks < 2; ++ks) {
        bf16x8 qf[2], kf[8];
        int c = ks * 4 + g;
#pragma unroll
        for (int fm = 0; fm < 2; ++fm) {
            int r = wq * 32 + fm * 16 + rl;
            qf[fm] = *(const bf16x8*)(smem + r * 128 + ((c ^ (r & 7)) << 4));
        }
#pragma unroll
        for (int fn = 0; fn < 8; ++fn) {
            int r = fn * 16 + rl;
            kf[fn] = *(const bf16x8*)(smem + AT_KOFF + r * 128 + ((c ^ (r & 7)) << 4));
        }
#pragma unroll
        for (int fm = 0; fm < 2; ++fm)
#pragma unroll
            for (int fn = 0; fn < 8; ++fn)
                accS[fm][fn] = __builtin_amdgcn_mfma_f32_16x16x32_bf16(
                    qf[fm], kf[fn], accS[fm][fn], 0, 0, 0);
    }

    // softmax (rows live in 16-lane groups)
#pragma unroll
    for (int fm = 0; fm < 2; ++fm)
#pragma unroll
        for (int v = 0; v < 4; ++v) {
            int i = wq * 32 + fm * 16 + g * 4 + v;
            float m = -1e30f;
#pragma unroll
            for (int fn = 0; fn < 8; ++fn) {
                int j = fn * 16 + rl;
                float s = accS[fm][fn][v] * 0.17677669529663687f + relb[j - i + 128];
                accS[fm][fn][v] = s;
                m = fmaxf(m, s);
            }
            m = fmaxf(m, __shfl_xor(m, 1));
            m = fmaxf(m, __shfl_xor(m, 2));
            m = fmaxf(m, __shfl_xor(m, 4));
            m = fmaxf(m, __shfl_xor(m, 8));
            float sum = 0.0f;
#pragma unroll
            for (int fn = 0; fn < 8; ++fn) {
                float p = __expf(accS[fm][fn][v] - m);
                accS[fm][fn][v] = p;
                sum += p;
            }
            sum += __shfl_xor(sum, 1);
            sum += __shfl_xor(sum, 2);
            sum += __shfl_xor(sum, 4);
            sum += __shfl_xor(sum, 8);
            float inv = 1.0f / sum;
#pragma unroll
            for (int fn = 0; fn < 8; ++fn) accS[fm][fn][v] *= inv;
        }

    __syncthreads();   // all Qc/Kc reads done before P overwrites them

    // write P [128][136] bf16 at offset 0
#pragma unroll
    for (int fm = 0; fm < 2; ++fm)
#pragma unroll
        for (int fn = 0; fn < 8; ++fn)
#pragma unroll
            for (int v = 0; v < 4; ++v) {
                int i = wq * 32 + fm * 16 + g * 4 + v;
                int j = fn * 16 + rl;
                ((unsigned short*)smem)[i * 136 + j] = f2bf(accS[fm][fn][v]);
            }
    __syncthreads();

    // O = P @ V   (combined cols: 0..31 = or, 32..63 = oi)
    f32x4 accO[2][4];
#pragma unroll
    for (int i = 0; i < 2; ++i)
#pragma unroll
        for (int j = 0; j < 4; ++j)
#pragma unroll
            for (int v = 0; v < 4; ++v) accO[i][j][v] = 0.0f;

#pragma unroll
    for (int ks = 0; ks < 4; ++ks) {
        bf16x8 pf[2], vf[4];
#pragma unroll
        for (int fm = 0; fm < 2; ++fm) {
            int r = wq * 32 + fm * 16 + rl;
            pf[fm] = *(const bf16x8*)(smem + r * 272 + ks * 64 + g * 16);
        }
#pragma unroll
        for (int fn = 0; fn < 4; ++fn) {
            int n = fn * 16 + rl;
            vf[fn] = *(const bf16x8*)(smem + AT_VOFF + n * 272 + ks * 64 + g * 16);
        }
#pragma unroll
        for (int fm = 0; fm < 2; ++fm)
#pragma unroll
            for (int fn = 0; fn < 4; ++fn)
                accO[fm][fn] = __builtin_amdgcn_mfma_f32_16x16x32_bf16(
                    pf[fm], vf[fn], accO[fm][fn], 0, 0, 0);
    }

#pragma unroll
    for (int fm = 0; fm < 2; ++fm)
#pragma unroll
        for (int fn = 0; fn < 4; ++fn)
#pragma unroll
            for (int v = 0; v < 4; ++v) {
                int i = wq * 32 + fm * 16 + g * 4 + v;
                int dc = fn * 16 + rl;
                int col = (dc < 32) ? (h * 32 + dc) : (256 + h * 32 + (dc - 32));
                attout[(size_t)(tok0 + i) * 512 + col] = f2bf(accO[fm][fn][v]);
            }
}

// ----------------------------- launch --------------------------------------

extern "C" void kernel_launch(void* const* d_in, const int* in_sizes, int n_in,
                              void* d_out, int out_size, void* d_ws, size_t ws_size,
                              hipStream_t stream) {
    const float* x_real = (const float*)d_in[0];
    const float* x_imag = (const float*)d_in[1];
    const float* Wq_r = (const float*)d_in[2];
    const float* Wq_i = (const float*)d_in[3];
    const float* Wk_r = (const float*)d_in[4];
    const float* Wk_i = (const float*)d_in[5];
    const float* Wv_r = (const float*)d_in[6];
    const float* Wv_i = (const float*)d_in[7];
    const float* Wo_r = (const float*)d_in[8];
    const float* Wo_i = (const float*)d_in[9];
    const float* rel_bias = (const float*)d_in[10];
    const float* norm1 = (const float*)d_in[11];
    const float* norm2 = (const float*)d_in[12];
    const float* W1_r = (const float*)d_in[13];
    const float* b1_r = (const float*)d_in[14];
    const float* W1_i = (const float*)d_in[15];
    const float* b1_i = (const float*)d_in[16];
    const float* W2_r = (const float*)d_in[17];
    const float* b2_r = (const float*)d_in[18];
    const float* W2_i = (const float*)d_in[19];
    const float* b2_i = (const float*)d_in[20];

    float* X = (float*)d_out;                       // planar residual stream

    char* ws = (char*)d_ws;
    unsigned short* NRM  = (unsigned short*)(ws + 0);           // 16 MB
    unsigned short* QKVH = (unsigned short*)(ws + 16777216);    // 64 MB (QKV / FFN-H)
    unsigned short* ATTO = (unsigned short*)(ws + 83886080);    // 16 MB
    unsigned short* WQKV = (unsigned short*)(ws + 100663296);   // 6 MB
    unsigned short* WO   = (unsigned short*)(ws + 106954752);   // 2 MB
    unsigned short* W1P  = (unsigned short*)(ws + 109051904);   // 8 MB
    unsigned short* W2P  = (unsigned short*)(ws + 117440512);   // 8 MB
    float*          B1   = (float*)(ws + 125829120);
    float*          B2   = (float*)(ws + 125861888);

    copyin_kernel<<<8192, 256, 0, stream>>>(x_real, x_imag, X);
    pack_qkv_kernel<<<12288, 256, 0, stream>>>(Wq_r, Wq_i, Wk_r, Wk_i, Wv_r, Wv_i, WQKV);
    pack_o_kernel<<<4096, 256, 0, stream>>>(Wo_r, Wo_i, WO);
    pack_ffn1_kernel<<<16384, 256, 0, stream>>>(W1_r, W1_i, W1P);
    pack_ffn2_kernel<<<16384, 256, 0, stream>>>(W2_r, W2_i, W2P);
    pack_bias_kernel<<<40, 256, 0, stream>>>(b1_r, b1_i, b2_r, b2_i, B1, B2);

    for (int l = 0; l < 4; ++l) {
        rmsnorm_kernel<<<4096, 256, 0, stream>>>(X, norm1 + l * 256, NRM);
        gemm3_kernel<0><<<1536, 256, 0, stream>>>(
            NRM, WQKV + (size_t)l * 786432, QKVH, nullptr, nullptr, 512, 1536, 12);
        attn_kernel<<<dim3(64, 8, 2), 256, 0, stream>>>(QKVH, rel_bias + l * 257, ATTO);
        gemm3_kernel<2><<<512, 256, 0, stream>>>(
            ATTO, WO + (size_t)l * 262144, nullptr, nullptr, X, 512, 512, 4);
        rmsnorm_kernel<<<4096, 256, 0, stream>>>(X, norm2 + l * 256, NRM);
        gemm3_kernel<1><<<2048, 256, 0, stream>>>(
            NRM, W1P + (size_t)l * 1048576, QKVH, B1 + l * 2048, nullptr, 512, 2048, 16);
        gemm3_kernel<2><<<512, 256, 0, stream>>>(
            QKVH, W2P + (size_t)l * 1048576, nullptr, B2 + l * 512, X, 2048, 512, 4);
    }
}

// Round 8
// 983.049 us; speedup vs baseline: 1.3203x; 1.0564x over previous
//
#include <hip/hip_runtime.h>
#include <cstdint>

// ---------------------------------------------------------------------------
// CVTransformer: L=4, D=256, H=8, DH=32, WS=128, FF=1024, B=2, N=8192
// Residual stream X = d_out, planar fp32 [2][16384][256] (real, imag planes).
// All matmuls bf16 MFMA GEMMs with K = 2*D (real|imag along K in A/NRM).
// GEMM: BM=BN=128, 4 waves, 2x32KB dbuf (2 blocks/CU), counted-vmcnt(8)
// cross-barrier prefetch.  K is a COMPILE-TIME template param; K-loop fully
// unrolled; all global/LDS addresses precomputed once and pointer-advanced
// (kills the VALU address-recompute that capped MfmaUtil at ~20%).
// ---------------------------------------------------------------------------

typedef __bf16 bf16x8 __attribute__((ext_vector_type(8)));
typedef float  f32x4  __attribute__((ext_vector_type(4)));

#define M_TOK 16384
#define PLANE 4194304   // 16384*256 floats per plane

__device__ __forceinline__ unsigned short f2bf(float f) {
    union { float f; unsigned int u; } v; v.f = f;
    unsigned int r = v.u + 0x7FFFu + ((v.u >> 16) & 1u);
    return (unsigned short)(r >> 16);
}

__device__ __forceinline__ void async16(const void* g, void* l) {
    __builtin_amdgcn_global_load_lds(
        (const __attribute__((address_space(1))) void*)g,
        (__attribute__((address_space(3))) void*)l, 16, 0, 0);
}

// ----------------------------- elementwise ---------------------------------

__global__ __launch_bounds__(256) void copyin_kernel(const float* __restrict__ xr,
                                                     const float* __restrict__ xi,
                                                     float* __restrict__ X) {
    int idx = blockIdx.x * 256 + threadIdx.x;       // float4 over [2][16384][64]
    int p = idx >> 20;                               // 1048576 f4 per plane
    int rem = idx & 1048575;
    ((float4*)X)[idx] = p ? ((const float4*)xi)[rem] : ((const float4*)xr)[rem];
}

// ----------------------------- weight packing ------------------------------

__global__ __launch_bounds__(256) void pack_qkv_kernel(
    const float* __restrict__ Wq_r, const float* __restrict__ Wq_i,
    const float* __restrict__ Wk_r, const float* __restrict__ Wk_i,
    const float* __restrict__ Wv_r, const float* __restrict__ Wv_i,
    unsigned short* __restrict__ out) {
    int idx = blockIdx.x * 256 + threadIdx.x;       // L*1536*512
    int l = idx / 786432;
    int rem = idx - l * 786432;
    int n = rem >> 9, k = rem & 511;
    int blk = n >> 8;                                // 0..5 : qr qi kr ki vr vi
    int no = n & 255, kk = k & 255;
    bool khi = (k >= 256);
    bool imag = (blk & 1);
    const float *Wr, *Wi;
    int proj = blk >> 1;
    if (proj == 0)      { Wr = Wq_r; Wi = Wq_i; }
    else if (proj == 1) { Wr = Wk_r; Wi = Wk_i; }
    else                { Wr = Wv_r; Wi = Wv_i; }
    int wi = l * 65536 + kk * 256 + no;
    float val = !imag ? (khi ? -Wi[wi] : Wr[wi])
                      : (khi ?  Wr[wi] : Wi[wi]);
    out[idx] = f2bf(val);
}

__global__ __launch_bounds__(256) void pack_o_kernel(
    const float* __restrict__ Wo_r, const float* __restrict__ Wo_i,
    unsigned short* __restrict__ out) {
    int idx = blockIdx.x * 256 + threadIdx.x;       // L*512*512
    int l = idx >> 18;
    int rem = idx & 262143;
    int n = rem >> 9, k = rem & 511;
    bool imag = (n >= 256);
    int no = n & 255, kk = k & 255;
    bool khi = (k >= 256);
    int wi = l * 65536 + kk * 256 + no;
    float val = !imag ? (khi ? -Wo_i[wi] : Wo_r[wi])
                      : (khi ?  Wo_r[wi] : Wo_i[wi]);
    out[idx] = f2bf(val);
}

__global__ __launch_bounds__(256) void pack_ffn1_kernel(
    const float* __restrict__ W1_r, const float* __restrict__ W1_i,
    unsigned short* __restrict__ out) {
    int idx = blockIdx.x * 256 + threadIdx.x;       // L*2048*512
    int l = idx >> 20;
    int rem = idx & 1048575;
    int n = rem >> 9, k = rem & 511;
    bool imag = (n >= 1024);
    int no = imag ? n - 1024 : n;
    int kk = k & 255;
    bool khi = (k >= 256);
    int wi = l * 262144 + kk * 1024 + no;
    float val = !imag ? (khi ? -W1_i[wi] : W1_r[wi])
                      : (khi ?  W1_r[wi] : W1_i[wi]);
    out[idx] = f2bf(val);
}

__global__ __launch_bounds__(256) void pack_ffn2_kernel(
    const float* __restrict__ W2_r, const float* __restrict__ W2_i,
    unsigned short* __restrict__ out) {
    int idx = blockIdx.x * 256 + threadIdx.x;       // L*512*2048
    int l = idx >> 20;
    int rem = idx & 1048575;
    int n = rem >> 11, k = rem & 2047;
    bool imag = (n >= 256);
    int no = n & 255;
    int kk = k & 1023;
    bool khi = (k >= 1024);
    int wi = l * 262144 + kk * 256 + no;
    float val = !imag ? (khi ? -W2_i[wi] : W2_r[wi])
                      : (khi ?  W2_r[wi] : W2_i[wi]);
    out[idx] = f2bf(val);
}

__global__ __launch_bounds__(256) void pack_bias_kernel(
    const float* __restrict__ b1r, const float* __restrict__ b1i,
    const float* __restrict__ b2r, const float* __restrict__ b2i,
    float* __restrict__ B1, float* __restrict__ B2) {
    int idx = blockIdx.x * 256 + threadIdx.x;       // 4*2048 + 4*512 = 10240
    if (idx < 8192) {
        int l = idx >> 11, n = idx & 2047;
        bool imag = (n >= 1024);
        int no = imag ? n - 1024 : n;
        int bi = l * 1024 + no;
        B1[idx] = imag ? (b1r[bi] + b1i[bi]) : (b1r[bi] - b1i[bi]);
    } else {
        int i2 = idx - 8192;
        int l = i2 >> 9, n = i2 & 511;
        bool imag = (n >= 256);
        int no = n & 255;
        int bi = l * 256 + no;
        B2[i2] = imag ? (b2r[bi] + b2i[bi]) : (b2r[bi] - b2i[bi]);
    }
}

// ----------------------------- rmsnorm -------------------------------------

__global__ __launch_bounds__(256) void rmsnorm_kernel(const float* __restrict__ X,
                                                      const float* __restrict__ scale,
                                                      unsigned short* __restrict__ out) {
    int row = blockIdx.x * 4 + (threadIdx.x >> 6);
    int lane = threadIdx.x & 63;
    float4 xr = ((const float4*)(X + (size_t)row * 256))[lane];
    float4 xi = ((const float4*)(X + PLANE + (size_t)row * 256))[lane];
    float ss = xr.x * xr.x + xr.y * xr.y + xr.z * xr.z + xr.w * xr.w
             + xi.x * xi.x + xi.y * xi.y + xi.z * xi.z + xi.w * xi.w;
#pragma unroll
    for (int m = 1; m < 64; m <<= 1) ss += __shfl_xor(ss, m);
    float inv = 1.0f / sqrtf(ss * (1.0f / 256.0f) + 1e-8f);
    float4 sc = ((const float4*)scale)[lane];
    ushort4 o0, o1;
    o0.x = f2bf(xr.x * inv * sc.x); o0.y = f2bf(xr.y * inv * sc.y);
    o0.z = f2bf(xr.z * inv * sc.z); o0.w = f2bf(xr.w * inv * sc.w);
    o1.x = f2bf(xi.x * inv * sc.x); o1.y = f2bf(xi.y * inv * sc.y);
    o1.z = f2bf(xi.z * inv * sc.z); o1.w = f2bf(xi.w * inv * sc.w);
    ushort4* orow = (ushort4*)(out + (size_t)row * 512);
    orow[lane] = o0;
    orow[64 + lane] = o1;
}

// ----------------------------- GEMM ----------------------------------------
// C[M,N] = A[M,K](bf16) @ Bt[N,K]^T(bf16).  BM=BN=128, BK=64, 4 waves,
// 2 x 32KB LDS dbuf (2 blocks/CU).  K compile-time; loop fully unrolled.
// All staging pointers / LDS offsets precomputed once; pointers advance by
// +64 elems per staged tile.  vmcnt(8): tile t landed, t+1 in flight.
// MODE 0: bf16 out. 1: +bias, exact GELU, bf16. 2: +bias(opt), fp32 += planar X.

template <int K, int MODE>
__global__ __launch_bounds__(256, 2) void gemm4_kernel(
    const unsigned short* __restrict__ A, const unsigned short* __restrict__ Bt,
    unsigned short* __restrict__ Obf, const float* __restrict__ bias,
    float* __restrict__ Xres, int N, int nTn) {
    constexpr int NT = K >> 6;
    __shared__ __align__(16) char smem[65536];
    const int tid = threadIdx.x;
    const int lane = tid & 63;
    const int wave = tid >> 6;
    const int g = lane >> 4, rl = lane & 15;
    const int wm = wave >> 1, wn = wave & 1;

    // T1: bijective XCD-chunk swizzle (nwg % 8 == 0 for every launch)
    const int nwg = gridDim.x;
    const int qs = nwg >> 3;
    const int wg = (blockIdx.x & 7) * qs + (blockIdx.x >> 3);
    const int tM = wg / nTn, tN = wg - tM * nTn;

    // ---- precompute staging addresses (once) ----
    const unsigned short* pA[4];
    const unsigned short* pB[4];
    int dA[4], dB[4];
#pragma unroll
    for (int it = 0; it < 4; ++it) {
        int s = it * 256 + tid;
        int r = s >> 3, c = (s & 7) ^ (r & 7);
        pA[it] = A + (size_t)(tM * 128 + r) * K + c * 8;
        pB[it] = Bt + (size_t)(tN * 128 + r) * K + c * 8;
        dA[it] = (it * 256 + wave * 64) * 16;
        dB[it] = 16384 + (it * 256 + wave * 64) * 16;
    }
    // ---- precompute fragment LDS byte offsets (once) ----
    int offA[2][4], offB[2][4];
#pragma unroll
    for (int ks = 0; ks < 2; ++ks) {
        int c = ks * 4 + g;
#pragma unroll
        for (int f = 0; f < 4; ++f) {
            int hrA = wm * 64 + f * 16 + rl;
            offA[ks][f] = hrA * 128 + ((c ^ (hrA & 7)) << 4);
            int hrB = wn * 64 + f * 16 + rl;
            offB[ks][f] = 16384 + hrB * 128 + ((c ^ (hrB & 7)) << 4);
        }
    }

    f32x4 acc[4][4];
#pragma unroll
    for (int i = 0; i < 4; ++i)
#pragma unroll
        for (int j = 0; j < 4; ++j)
#pragma unroll
            for (int v = 0; v < 4; ++v) acc[i][j][v] = 0.0f;

    // prologue: stage tiles 0 and 1 (pointers advance 64 elems per stage)
#pragma unroll
    for (int b = 0; b < 2; ++b) {
#pragma unroll
        for (int it = 0; it < 4; ++it) {
            async16(pA[it], smem + b * 32768 + dA[it]);
            async16(pB[it], smem + b * 32768 + dB[it]);
        }
#pragma unroll
        for (int it = 0; it < 4; ++it) { pA[it] += 64; pB[it] += 64; }
    }

#pragma unroll
    for (int t = 0; t < NT; ++t) {
        if (t + 1 < NT) asm volatile("s_waitcnt vmcnt(8)" ::: "memory");
        else            asm volatile("s_waitcnt vmcnt(0)" ::: "memory");
        __builtin_amdgcn_s_barrier();
        const int cur = (t & 1) * 32768;
#pragma unroll
        for (int ks = 0; ks < 2; ++ks) {
            bf16x8 aF[4], bF[4];
#pragma unroll
            for (int f = 0; f < 4; ++f) {
                aF[f] = *(const bf16x8*)(smem + cur + offA[ks][f]);
                bF[f] = *(const bf16x8*)(smem + cur + offB[ks][f]);
            }
#pragma unroll
            for (int fm = 0; fm < 4; ++fm)
#pragma unroll
                for (int fn = 0; fn < 4; ++fn)
                    acc[fm][fn] = __builtin_amdgcn_mfma_f32_16x16x32_bf16(
                        aF[fm], bF[fn], acc[fm][fn], 0, 0, 0);
        }
        __builtin_amdgcn_s_barrier();
        if (t + 2 < NT) {
#pragma unroll
            for (int it = 0; it < 4; ++it) {
                async16(pA[it], smem + cur + dA[it]);
                async16(pB[it], smem + cur + dB[it]);
            }
#pragma unroll
            for (int it = 0; it < 4; ++it) { pA[it] += 64; pB[it] += 64; }
        }
    }

#pragma unroll
    for (int fm = 0; fm < 4; ++fm)
#pragma unroll
        for (int fn = 0; fn < 4; ++fn)
#pragma unroll
            for (int v = 0; v < 4; ++v) {
                int row = tM * 128 + wm * 64 + fm * 16 + g * 4 + v;
                int col = tN * 128 + wn * 64 + fn * 16 + rl;
                float val = acc[fm][fn][v];
                if (MODE == 0) {
                    Obf[(size_t)row * N + col] = f2bf(val);
                } else if (MODE == 1) {
                    float x = val + bias[col];
                    float ge = 0.5f * x * (1.0f + erff(x * 0.70710678118654752f));
                    Obf[(size_t)row * N + col] = f2bf(ge);
                } else {
                    float x = val + (bias ? bias[col] : 0.0f);
                    size_t off = (col < 256 ? 0 : (size_t)PLANE)
                               + (size_t)row * 256 + (col & 255);
                    Xres[off] += x;
                }
            }
}

// ----------------------------- windowed attention --------------------------
// One block per (window, head, batch).  QKV buffer: [16384][1536] bf16,
// cols: qr qi kr ki vr vi (256 each).  Output: [16384][512] bf16 (or|oi).

#define AT_KOFF 16384
#define AT_VOFF 34816
#define AT_ROFF 52224

__global__ __launch_bounds__(256) void attn_kernel(
    const unsigned short* __restrict__ qkv, const float* __restrict__ relb_g,
    unsigned short* __restrict__ attout) {
    __shared__ __align__(16) char smem[53264];
    const int tid = threadIdx.x;
    const int lane = tid & 63;
    const int wq = tid >> 6;
    const int g = lane >> 4;
    const int rl = lane & 15;
    const int w = blockIdx.x, h = blockIdx.y, b = blockIdx.z;
    const int tok0 = b * 8192 + w * 128;
    float* relb = (float*)(smem + AT_ROFF);

    for (int i = tid; i < 257; i += 256) relb[i] = relb_g[i];

    // stage Qc,Kc [128][64] bf16 (real|imag along K), XOR chunk swizzle
#pragma unroll
    for (int it = 0; it < 4; ++it) {
        int s = it * 256 + tid;
        int r = s >> 3;
        int c = (s & 7) ^ (r & 7);
        int colq = (c < 4) ? (h * 32 + c * 8) : (256 + h * 32 + (c - 4) * 8);
        const unsigned short* rowp = qkv + (size_t)(tok0 + r) * 1536;
        *(float4*)(smem + s * 16) = *(const float4*)(rowp + colq);
        *(float4*)(smem + AT_KOFF + s * 16) = *(const float4*)(rowp + colq + 512);
    }
    // stage Vt [64][136] bf16: Vt[d'][j] ; d' 0..31 = vr, 32..63 = vi
#pragma unroll
    for (int it = 0; it < 4; ++it) {
        int e = it * 256 + tid;
        int j = e >> 3;
        int d0 = (e & 7) * 8;
        int colv = (d0 < 32) ? (1024 + h * 32 + d0) : (1280 + h * 32 + (d0 - 32));
        float4 vv = *(const float4*)(qkv + (size_t)(tok0 + j) * 1536 + colv);
        const unsigned short* u = (const unsigned short*)&vv;
#pragma unroll
        for (int k = 0; k < 8; ++k)
            *(unsigned short*)(smem + AT_VOFF + ((d0 + k) * 136 + j) * 2) = u[k];
    }
    __syncthreads();

    // S = Qc @ Kc^T  (covers qr.kr + qi.ki via K=64)
    f32x4 accS[2][8];
#pragma unroll
    for (int i = 0; i < 2; ++i)
#pragma unroll
        for (int j = 0; j < 8; ++j)
#pragma unroll
            for (int v = 0; v < 4; ++v) accS[i][j][v] = 0.0f;

#pragma unroll
    for (int ks = 0; ks < 2; ++ks) {
        bf16x8 qf[2], kf[8];
        int c = ks * 4 + g;
#pragma unroll
        for (int fm = 0; fm < 2; ++fm) {
            int r = wq * 32 + fm * 16 + rl;
            qf[fm] = *(const bf16x8*)(smem + r * 128 + ((c ^ (r & 7)) << 4));
        }
#pragma unroll
        for (int fn = 0; fn < 8; ++fn) {
            int r = fn * 16 + rl;
            kf[fn] = *(const bf16x8*)(smem + AT_KOFF + r * 128 + ((c ^ (r & 7)) << 4));
        }
#pragma unroll
        for (int fm = 0; fm < 2; ++fm)
#pragma unroll
            for (int fn = 0; fn < 8; ++fn)
                accS[fm][fn] = __builtin_amdgcn_mfma_f32_16x16x32_bf16(
                    qf[fm], kf[fn], accS[fm][fn], 0, 0, 0);
    }

    // softmax (rows live in 16-lane groups)
#pragma unroll
    for (int fm = 0; fm < 2; ++fm)
#pragma unroll
        for (int v = 0; v < 4; ++v) {
            int i = wq * 32 + fm * 16 + g * 4 + v;
            float m = -1e30f;
#pragma unroll
            for (int fn = 0; fn < 8; ++fn) {
                int j = fn * 16 + rl;
                float s = accS[fm][fn][v] * 0.17677669529663687f + relb[j - i + 128];
                accS[fm][fn][v] = s;
                m = fmaxf(m, s);
            }
            m = fmaxf(m, __shfl_xor(m, 1));
            m = fmaxf(m, __shfl_xor(m, 2));
            m = fmaxf(m, __shfl_xor(m, 4));
            m = fmaxf(m, __shfl_xor(m, 8));
            float sum = 0.0f;
#pragma unroll
            for (int fn = 0; fn < 8; ++fn) {
                float p = __expf(accS[fm][fn][v] - m);
                accS[fm][fn][v] = p;
                sum += p;
            }
            sum += __shfl_xor(sum, 1);
            sum += __shfl_xor(sum, 2);
            sum += __shfl_xor(sum, 4);
            sum += __shfl_xor(sum, 8);
            float inv = 1.0f / sum;
#pragma unroll
            for (int fn = 0; fn < 8; ++fn) accS[fm][fn][v] *= inv;
        }

    __syncthreads();   // all Qc/Kc reads done before P overwrites them

    // write P [128][136] bf16 at offset 0
#pragma unroll
    for (int fm = 0; fm < 2; ++fm)
#pragma unroll
        for (int fn = 0; fn < 8; ++fn)
#pragma unroll
            for (int v = 0; v < 4; ++v) {
                int i = wq * 32 + fm * 16 + g * 4 + v;
                int j = fn * 16 + rl;
                ((unsigned short*)smem)[i * 136 + j] = f2bf(accS[fm][fn][v]);
            }
    __syncthreads();

    // O = P @ V   (combined cols: 0..31 = or, 32..63 = oi)
    f32x4 accO[2][4];
#pragma unroll
    for (int i = 0; i < 2; ++i)
#pragma unroll
        for (int j = 0; j < 4; ++j)
#pragma unroll
            for (int v = 0; v < 4; ++v) accO[i][j][v] = 0.0f;

#pragma unroll
    for (int ks = 0; ks < 4; ++ks) {
        bf16x8 pf[2], vf[4];
#pragma unroll
        for (int fm = 0; fm < 2; ++fm) {
            int r = wq * 32 + fm * 16 + rl;
            pf[fm] = *(const bf16x8*)(smem + r * 272 + ks * 64 + g * 16);
        }
#pragma unroll
        for (int fn = 0; fn < 4; ++fn) {
            int n = fn * 16 + rl;
            vf[fn] = *(const bf16x8*)(smem + AT_VOFF + n * 272 + ks * 64 + g * 16);
        }
#pragma unroll
        for (int fm = 0; fm < 2; ++fm)
#pragma unroll
            for (int fn = 0; fn < 4; ++fn)
                accO[fm][fn] = __builtin_amdgcn_mfma_f32_16x16x32_bf16(
                    pf[fm], vf[fn], accO[fm][fn], 0, 0, 0);
    }

#pragma unroll
    for (int fm = 0; fm < 2; ++fm)
#pragma unroll
        for (int fn = 0; fn < 4; ++fn)
#pragma unroll
            for (int v = 0; v < 4; ++v) {
                int i = wq * 32 + fm * 16 + g * 4 + v;
                int dc = fn * 16 + rl;
                int col = (dc < 32) ? (h * 32 + dc) : (256 + h * 32 + (dc - 32));
                attout[(size_t)(tok0 + i) * 512 + col] = f2bf(accO[fm][fn][v]);
            }
}

// ----------------------------- launch --------------------------------------

extern "C" void kernel_launch(void* const* d_in, const int* in_sizes, int n_in,
                              void* d_out, int out_size, void* d_ws, size_t ws_size,
                              hipStream_t stream) {
    const float* x_real = (const float*)d_in[0];
    const float* x_imag = (const float*)d_in[1];
    const float* Wq_r = (const float*)d_in[2];
    const float* Wq_i = (const float*)d_in[3];
    const float* Wk_r = (const float*)d_in[4];
    const float* Wk_i = (const float*)d_in[5];
    const float* Wv_r = (const float*)d_in[6];
    const float* Wv_i = (const float*)d_in[7];
    const float* Wo_r = (const float*)d_in[8];
    const float* Wo_i = (const float*)d_in[9];
    const float* rel_bias = (const float*)d_in[10];
    const float* norm1 = (const float*)d_in[11];
    const float* norm2 = (const float*)d_in[12];
    const float* W1_r = (const float*)d_in[13];
    const float* b1_r = (const float*)d_in[14];
    const float* W1_i = (const float*)d_in[15];
    const float* b1_i = (const float*)d_in[16];
    const float* W2_r = (const float*)d_in[17];
    const float* b2_r = (const float*)d_in[18];
    const float* W2_i = (const float*)d_in[19];
    const float* b2_i = (const float*)d_in[20];

    float* X = (float*)d_out;                       // planar residual stream

    char* ws = (char*)d_ws;
    unsigned short* NRM  = (unsigned short*)(ws + 0);           // 16 MB
    unsigned short* QKVH = (unsigned short*)(ws + 16777216);    // 64 MB (QKV / FFN-H)
    unsigned short* ATTO = (unsigned short*)(ws + 83886080);    // 16 MB
    unsigned short* WQKV = (unsigned short*)(ws + 100663296);   // 6 MB
    unsigned short* WO   = (unsigned short*)(ws + 106954752);   // 2 MB
    unsigned short* W1P  = (unsigned short*)(ws + 109051904);   // 8 MB
    unsigned short* W2P  = (unsigned short*)(ws + 117440512);   // 8 MB
    float*          B1   = (float*)(ws + 125829120);
    float*          B2   = (float*)(ws + 125861888);

    copyin_kernel<<<8192, 256, 0, stream>>>(x_real, x_imag, X);
    pack_qkv_kernel<<<12288, 256, 0, stream>>>(Wq_r, Wq_i, Wk_r, Wk_i, Wv_r, Wv_i, WQKV);
    pack_o_kernel<<<4096, 256, 0, stream>>>(Wo_r, Wo_i, WO);
    pack_ffn1_kernel<<<16384, 256, 0, stream>>>(W1_r, W1_i, W1P);
    pack_ffn2_kernel<<<16384, 256, 0, stream>>>(W2_r, W2_i, W2P);
    pack_bias_kernel<<<40, 256, 0, stream>>>(b1_r, b1_i, b2_r, b2_i, B1, B2);

    for (int l = 0; l < 4; ++l) {
        rmsnorm_kernel<<<4096, 256, 0, stream>>>(X, norm1 + l * 256, NRM);
        gemm4_kernel<512, 0><<<1536, 256, 0, stream>>>(
            NRM, WQKV + (size_t)l * 786432, QKVH, nullptr, nullptr, 1536, 12);
        attn_kernel<<<dim3(64, 8, 2), 256, 0, stream>>>(QKVH, rel_bias + l * 257, ATTO);
        gemm4_kernel<512, 2><<<512, 256, 0, stream>>>(
            ATTO, WO + (size_t)l * 262144, nullptr, nullptr, X, 512, 4);
        rmsnorm_kernel<<<4096, 256, 0, stream>>>(X, norm2 + l * 256, NRM);
        gemm4_kernel<512, 1><<<2048, 256, 0, stream>>>(
            NRM, W1P + (size_t)l * 1048576, QKVH, B1 + l * 2048, nullptr, 2048, 16);
        gemm4_kernel<2048, 2><<<512, 256, 0, stream>>>(
            QKVH, W2P + (size_t)l * 1048576, nullptr, B2 + l * 512, X, 512, 4);
    }
}